// Round 14
// baseline (279.724 us; speedup 1.0000x reference)
//
#include <hip/hip_runtime.h>
#include <hip/hip_bf16.h>

// Problem constants
#define Bc   4
#define Tc   1024
#define Cc   768
#define Hc   12
#define HSc  64
#define VDc  128
#define NQKV 4608   // gemm N for qkv (4*768 Q/K + 1536 V)
#define YLD  3072   // Y row stride: Q/K only (V goes to Vt)
#define NROWS 4096  // B*T
#define HVD  1536   // H*VD

// Y (qk) column offsets
#define Q1OFF 0
#define K1OFF 768
#define Q2OFF 1536
#define K2OFF 2304

typedef __bf16 bf16x8 __attribute__((ext_vector_type(8)));
typedef float f32x4 __attribute__((ext_vector_type(4)));
typedef unsigned int u32x4 __attribute__((ext_vector_type(4)));

// exp(s*0.125) == exp2(s * 0.125*log2(e))
#define EXP2SCALE 0.18033688011112042f

static __device__ __forceinline__ float bf2f(unsigned short s) {
    return __uint_as_float(((unsigned int)s) << 16);
}
static __device__ __forceinline__ unsigned short f2bf(float f) {
    unsigned int u = __float_as_uint(f);
    unsigned int r = (u + 0x7FFFu + ((u >> 16) & 1u)) >> 16;  // round-nearest-even
    return (unsigned short)r;
}
static __device__ __forceinline__ unsigned int pack2bf(float lo, float hi) {
    // bf16(lo) | bf16(hi)<<16, half-up rounding (values >= 0)
    unsigned int a = (__float_as_uint(lo) + 0x8000u) >> 16;
    unsigned int b = (__float_as_uint(hi) + 0x8000u) & 0xFFFF0000u;
    return a | b;
}
// raw v_exp_f32: 2^x without libm denorm guards (inputs bounded here)
static __device__ __forceinline__ float fast_exp2(float x) {
    float r;
    asm("v_exp_f32 %0, %1" : "=v"(r) : "v"(x));
    return r;
}

// async global->LDS 16B per lane; lds base must be wave-uniform
static __device__ __forceinline__ void load16_lds(const void* g, void* l) {
    __builtin_amdgcn_global_load_lds(
        (const __attribute__((address_space(1))) void*)g,
        (__attribute__((address_space(3))) void*)l, 16, 0, 0);
}

// ---------------------------------------------------------------------------
// prep: fused cast x->bf16 (blocks 0..3071), cast Wp->bf16 (3072..4223),
// lambda (4224..4235), zero-init out fp32 (4236..7307, for split-K atomics),
// trans_w weight transpose-repack (7308..8171).
// ---------------------------------------------------------------------------
__global__ __launch_bounds__(256) void prep(
    const float* __restrict__ x, const float* __restrict__ Wp,
    const float* __restrict__ lq1, const float* __restrict__ lk1,
    const float* __restrict__ lq2, const float* __restrict__ lk2,
    const int* __restrict__ layer_idx,
    const float* __restrict__ Wq1, const float* __restrict__ Wk1,
    const float* __restrict__ Wq2, const float* __restrict__ Wk2,
    const float* __restrict__ Wv,
    unsigned short* __restrict__ Xb, unsigned short* __restrict__ Wpb,
    float* __restrict__ lam, float* __restrict__ outz,
    unsigned short* __restrict__ WcatT)
{
    __shared__ float tile[64][65];
    int bid = blockIdx.x, tid = threadIdx.x;
    if (bid < 3072) {
        size_t i = (size_t)bid * 256 + tid;
        float4 v = *(const float4*)(x + i * 4);
        ushort4 u;
        u.x = f2bf(v.x); u.y = f2bf(v.y); u.z = f2bf(v.z); u.w = f2bf(v.w);
        *(ushort4*)(Xb + i * 4) = u;
    } else if (bid < 4224) {
        size_t i = (size_t)(bid - 3072) * 256 + tid;
        float4 v = *(const float4*)(Wp + i * 4);
        ushort4 u;
        u.x = f2bf(v.x); u.y = f2bf(v.y); u.z = f2bf(v.z); u.w = f2bf(v.w);
        *(ushort4*)(Wpb + i * 4) = u;
    } else if (bid < 4236) {
        if (tid < 64) {
            int h = bid - 4224, l = tid;
            float li = (float)layer_idx[0];
            float dyn = 0.8f - 0.6f * expf(-0.3f * (li - 1.0f));
            int i = h * HSc + l;
            float v = expf(lq1[i] * lk1[i]) - expf(lq2[i] * lk2[i]) + dyn;
            #pragma unroll
            for (int off = 32; off; off >>= 1) v += __shfl_xor(v, off);
            if (l == 0) lam[h] = v * (1.0f / 64.0f);
        }
    } else if (bid < 7308) {
        size_t i = (size_t)(bid - 4236) * 256 + tid;
        float4 z = {0.f, 0.f, 0.f, 0.f};
        *(float4*)(outz + i * 4) = z;
    } else {
        // trans_w: repack 5 projection weights into WcatT[n][k], k-contig
        int t = bid - 7308;
        int kt = t % 12, nt = t / 12;
        int k0 = kt * 64, n0 = nt * 64;
        const float* src;
        int stride;
        if (n0 < 3072) {
            int which = n0 / 768, m = n0 - which * 768, h = m >> 6;
            const float* W = (which == 0) ? Wq1 : (which == 1) ? Wk1 : (which == 2) ? Wq2 : Wk2;
            src = W + ((size_t)h * 768 + k0) * 64;
            stride = 64;
        } else {
            int rel = n0 - 3072, h = rel >> 7, e0 = rel & 127;
            src = Wv + ((size_t)h * 768 + k0) * 128 + e0;
            stride = 128;
        }
        for (int i = tid; i < 4096; i += 256) {
            int kl = i >> 6, dl = i & 63;
            tile[dl][kl] = src[(size_t)kl * stride + dl];
        }
        __syncthreads();
        for (int i = tid; i < 4096; i += 256) {
            int nl = i >> 6, kl = i & 63;
            WcatT[(size_t)(n0 + nl) * 768 + k0 + kl] = f2bf(tile[nl][kl]);
        }
    }
}

// ---------------------------------------------------------------------------
// MFMA GEMM — R18 (frozen): ring pipeline + XCD-chunked swizzle + split-K.
// ---------------------------------------------------------------------------
template<int TN, int KD, int LDC, bool OUT_BIAS, bool SPLITV, int KSPLIT>
__global__ __launch_bounds__(256) void gemm_mfma(
    const unsigned short* __restrict__ A, const unsigned short* __restrict__ Bt,
    unsigned short* __restrict__ Cb, float* __restrict__ Cf,
    const float* __restrict__ bias, unsigned short* __restrict__ VtOut)
{
    constexpr int BN = TN * 32;
    constexpr int JB = TN / 2;
    constexpr int ASLOT = 128 * 64;           // ushorts: A halves (2x4096)
    constexpr int SLOT  = ASLOT + BN * 64;    // + B halves
    __shared__ unsigned short ring[2 * SLOT];
    int tid = threadIdx.x, lane = tid & 63, w = tid >> 6;
    int wm = w >> 1, wn = w & 1;

    // XCD-chunked swizzle decode
    int bid = blockIdx.x;
    int xcd = bid & 7;
    int idx = bid >> 3;
    int ks = 0;
    if (KSPLIT == 2) { ks = idx & 1; idx >>= 1; }
    int mi  = idx & 3;
    int ni  = idx >> 2;
    int m0 = (xcd * 4 + mi) * 128;
    int n0 = ni * BN;
    constexpr int KLOC = KD / KSPLIT;         // this block's K extent
    const int kBase = ks * KLOC;

    int lr = lane >> 2, lq = lane & 3;
    const unsigned short* gA[2];
    const unsigned short* gB[JB];
    #pragma unroll
    for (int j = 0; j < 2; ++j) {
        int row = w * 32 + j * 16 + lr;
        int qg = lq ^ ((row >> 1) & 3);
        gA[j] = A + (size_t)(m0 + row) * KD + kBase + qg * 8;
    }
    #pragma unroll
    for (int j = 0; j < JB; ++j) {
        int row = w * (JB * 16) + j * 16 + lr;
        int qg = lq ^ ((row >> 1) & 3);
        gB[j] = Bt + (size_t)(n0 + row) * KD + kBase + qg * 8;
    }

    int rr = lane & 15, qd = lane >> 4;
    int aOff[4], bOff[TN];
    #pragma unroll
    for (int i = 0; i < 4; ++i) {
        int row = wm * 64 + i * 16 + rr;
        int qs = qd ^ ((row >> 1) & 3);
        aOff[i] = row * 32 + qs * 8;
    }
    #pragma unroll
    for (int t = 0; t < TN; ++t) {
        int row = wn * (TN * 16) + t * 16 + rr;
        int qs = qd ^ ((row >> 1) & 3);
        bOff[t] = row * 32 + qs * 8;
    }

    auto stageG = [&](int k, int slot) {
        unsigned short* s = ring + slot * SLOT;
        int k64 = k * 64;
        load16_lds(gA[0] + k64,      s + (w * 2 + 0) * 512);
        load16_lds(gA[1] + k64,      s + (w * 2 + 1) * 512);
        load16_lds(gA[0] + k64 + 32, s + 4096 + (w * 2 + 0) * 512);
        load16_lds(gA[1] + k64 + 32, s + 4096 + (w * 2 + 1) * 512);
        #pragma unroll
        for (int j = 0; j < JB; ++j) {
            load16_lds(gB[j] + k64,      s + ASLOT + (w * JB + j) * 512);
            load16_lds(gB[j] + k64 + 32, s + ASLOT + BN * 32 + (w * JB + j) * 512);
        }
    };

    f32x4 acc[4][TN];
    #pragma unroll
    for (int i = 0; i < 4; ++i)
        #pragma unroll
        for (int t = 0; t < TN; ++t) acc[i][t] = {0.f, 0.f, 0.f, 0.f};

    constexpr int NT = KLOC / 64;
    stageG(0, 0);
    for (int k = 0; k < NT; ++k) {
        asm volatile("s_waitcnt vmcnt(0)\n\ts_barrier" ::: "memory");
        const unsigned short* s = ring + (k & 1) * SLOT;
        if (k + 1 < NT) stageG(k + 1, (k + 1) & 1);

        bf16x8 af0[4], af1[4], bf0[TN], bf1[TN];
        #pragma unroll
        for (int i = 0; i < 4; ++i) {
            af0[i] = *(const bf16x8*)(s + aOff[i]);
            af1[i] = *(const bf16x8*)(s + 4096 + aOff[i]);
        }
        #pragma unroll
        for (int t = 0; t < TN; ++t) {
            bf0[t] = *(const bf16x8*)(s + ASLOT + bOff[t]);
            bf1[t] = *(const bf16x8*)(s + ASLOT + BN * 32 + bOff[t]);
        }
        #pragma unroll
        for (int i = 0; i < 4; ++i)
            #pragma unroll
            for (int t = 0; t < TN; ++t) {
                acc[i][t] = __builtin_amdgcn_mfma_f32_16x16x32_bf16(af0[i], bf0[t], acc[i][t], 0, 0, 0);
                acc[i][t] = __builtin_amdgcn_mfma_f32_16x16x32_bf16(af1[i], bf1[t], acc[i][t], 0, 0, 0);
            }
    }

    #pragma unroll
    for (int t = 0; t < TN; ++t) {
        int col = n0 + wn * (TN * 16) + t * 16 + rr;
        if (SPLITV && col >= 3072) {
            int rel = col - 3072, hh = rel >> 7, e = rel & 127;
            #pragma unroll
            for (int i = 0; i < 4; ++i) {
                int row0 = m0 + wm * 64 + i * 16 + qd * 4;
                int b = row0 >> 10, tt = row0 & 1023;
                ushort4 pk;
                pk.x = f2bf(acc[i][t][0]); pk.y = f2bf(acc[i][t][1]);
                pk.z = f2bf(acc[i][t][2]); pk.w = f2bf(acc[i][t][3]);
                *(ushort4*)&VtOut[(size_t)((b * Hc + hh) * 128 + e) * 1024 + tt] = pk;
            }
        } else if (KSPLIT == 2) {
            float bv = (OUT_BIAS && ks == 0) ? bias[col] : 0.f;
            #pragma unroll
            for (int i = 0; i < 4; ++i) {
                #pragma unroll
                for (int r = 0; r < 4; ++r) {
                    int row = m0 + wm * 64 + i * 16 + qd * 4 + r;
                    atomicAdd(&Cf[(size_t)row * LDC + col], acc[i][t][r] + bv);
                }
            }
        } else {
            float bv = OUT_BIAS ? bias[col] : 0.f;
            #pragma unroll
            for (int i = 0; i < 4; ++i) {
                #pragma unroll
                for (int r = 0; r < 4; ++r) {
                    int row = m0 + wm * 64 + i * 16 + qd * 4 + r;
                    if (OUT_BIAS)
                        Cf[(size_t)row * LDC + col] = acc[i][t][r] + bv;
                    else
                        Cb[(size_t)row * LDC + col] = f2bf(acc[i][t][r]);
                }
            }
        }
    }
}

// ---------------------------------------------------------------------------
// MFMA differential flash attention — R22: K-only LDS ring (32KB) + direct
// per-wave V loads -> 3 blocks/CU (12 waves, 3/SIMD; was 2 blocks / 8 waves
// with the 64KB K+V ring). Mechanism: all 4 waves read the SAME V tile and
// Vt is L2-resident, so V LDS-staging only bought L1-line dedup at the cost
// of half the occupancy in a latency-bound kernel (MFMA 12%, VALU 29%, occ
// 9%). V loads issued right after the barrier (vfA then vfB), BEFORE
// stage(i+1), so PV-A waits vmcnt(12), PV-B vmcnt(4), and the K-stage is
// only drained at the next iteration top (1-deep prefetch preserved).
// V on VMEM pipe also unloads the DS pipe (K reads + bperms only).
// Staging: 4 waves x 4 loads (sub = wv&1, halfK = wv>>1).
// grid (48,16): x = bh (XCD-pinned), y -> g = 15-y; 768 blocks = 3/CU
// exactly; round-robin dispatch gives each CU ~(long+mid+short) blocks.
// R19 lesson kept: NO launch-bounds occupancy forcing (VGPR wall ~144).
// ---------------------------------------------------------------------------
__global__ __launch_bounds__(256) void diff_attn_mfma(
    const unsigned short* __restrict__ Y, const unsigned short* __restrict__ Vt,
    const float* __restrict__ lam_buf, unsigned short* __restrict__ attn)
{
    // 2 slots x 16KB: [subA: K1 0-4K | K2 4-8K][subB: +8K same]
    __shared__ __align__(16) unsigned short Kring[2 * 8192];  // 32 KB

    int bh = blockIdx.x;                          // fastest dim -> XCD-pinned
    int b = bh / Hc, h = bh - b * Hc;
    int g = 15 - (int)blockIdx.y;                 // longest first
    int tid = threadIdx.x, lane = tid & 63, wv = tid >> 6;
    int cl = lane & 15, qd = lane >> 4;
    float lamv = lam_buf[h];
    size_t rowbase = (size_t)(b * Tc) * YLD;
    const int hq = h * HSc;
    const unsigned short* VtB = Vt + ((size_t)bh << 17);   // bh*128*1024
    const f32x4 zero4 = {0.f, 0.f, 0.f, 0.f};

    // ---- K staging: 4 waves x 4 loads (1KB each) = 16KB per 64-key iter ----
    // sub = wv&1 (subtile), halfK = wv>>1 (segment group). seg 0-3: K1 rows
    // 0..31; seg 4-7: K2 rows 0..31. Inverse-XOR-swizzled global chunk.
    int sub   = wv & 1;
    int halfK = wv >> 1;
    int ksrow = lane >> 3;
    int ksch  = (lane & 7) ^ ksrow;
    int offk[4];
    #pragma unroll
    for (int j = 0; j < 4; ++j) {
        int seg = halfK * 4 + j;
        int moff = (seg < 4) ? K1OFF : K2OFF;
        offk[j] = ((seg & 3) * 8 + ksrow) * YLD + moff + hq + ksch * 8;
    }

    auto stage = [&](int i, int slot) {
        int kt = 2 * i + sub;
        char* base = (char*)Kring + slot * 16384 + sub * 8192 + halfK * 4096;
        const unsigned short* g0 = Y + rowbase + (size_t)(kt * 32) * YLD;
        #pragma unroll
        for (int j = 0; j < 4; ++j)
            load16_lds(g0 + offk[j], base + j * 1024);
    };

    // ---- K fragment LDS byte offsets within an 8KB subtile (swizzled) ----
    int kfo[2][4];
    #pragma unroll
    for (int c = 0; c < 2; ++c) {
        int row = c * 16 + cl;
        #pragma unroll
        for (int j = 0; j < 4; ++j)
            kfo[c][j] = (j >> 1) * 4096 + row * 128 +
                        ((((j & 1) * 4 + qd) ^ (row & 7)) << 4);
    }
    // ---- V direct-load global element offsets (kt-independent part) ----
    int vgo[8];
    #pragma unroll
    for (int ec = 0; ec < 8; ++ec)
        vgo[ec] = ((ec * 16 + cl) << 10) + qd * 8;

    // P-transform bpermute indices (byte = srclane*4)
    int idxA = ((32 * (qd & 1)) + cl) * 4;
    int idxB = idxA + 64;
    bool loHalf = (qd < 2);

    int qrow = g * 64 + wv * 16;

    stage(0, 0);

    size_t qoff = rowbase + (size_t)(qrow + cl) * YLD;
    bf16x8 q1a = *(const bf16x8*)(Y + qoff + Q1OFF + hq + qd * 8);
    bf16x8 q1b = *(const bf16x8*)(Y + qoff + Q1OFF + hq + 32 + qd * 8);
    bf16x8 q2a = *(const bf16x8*)(Y + qoff + Q2OFF + hq + qd * 8);
    bf16x8 q2b = *(const bf16x8*)(Y + qoff + Q2OFF + hq + 32 + qd * 8);

    f32x4 O1[8], O2[8];
    #pragma unroll
    for (int ec = 0; ec < 8; ++ec) { O1[ec] = zero4; O2[ec] = zero4; }
    float l1s = 0.f, l2s = 0.f;

    // mask + exp + pack + cross-lane gather for one 32-key subtile
    auto transform = [&](f32x4 S1[2], f32x4 S2[2], int kt,
                         bf16x8& pa1o, bf16x8& pa2o) {
        if (kt * 32 + 31 > qrow) {
            #pragma unroll
            for (int c = 0; c < 2; ++c) {
                int lim = qrow + cl - kt * 32 - c * 16 - qd * 4;
                #pragma unroll
                for (int r = 0; r < 4; ++r) {
                    if (r > lim) { S1[c][r] = -1e30f; S2[c][r] = -1e30f; }
                }
            }
        }
        float p1v[2][4], p2v[2][4];
        #pragma unroll
        for (int c = 0; c < 2; ++c) {
            #pragma unroll
            for (int r = 0; r < 4; ++r) {
                p1v[c][r] = fast_exp2(S1[c][r] * EXP2SCALE);
                p2v[c][r] = fast_exp2(S2[c][r] * EXP2SCALE);
                l1s += p1v[c][r];
                l2s += p2v[c][r];
            }
        }
        unsigned int s1m[2][2], s2m[2][2];
        #pragma unroll
        for (int c = 0; c < 2; ++c) {
            s1m[c][0] = pack2bf(p1v[c][0], p1v[c][1]);
            s1m[c][1] = pack2bf(p1v[c][2], p1v[c][3]);
            s2m[c][0] = pack2bf(p2v[c][0], p2v[c][1]);
            s2m[c][1] = pack2bf(p2v[c][2], p2v[c][3]);
        }
        u32x4 U1, U2;
        {
            int a00 = __builtin_amdgcn_ds_bpermute(idxA, (int)s1m[0][0]);
            int a10 = __builtin_amdgcn_ds_bpermute(idxA, (int)s1m[1][0]);
            int a01 = __builtin_amdgcn_ds_bpermute(idxA, (int)s1m[0][1]);
            int a11 = __builtin_amdgcn_ds_bpermute(idxA, (int)s1m[1][1]);
            int b00 = __builtin_amdgcn_ds_bpermute(idxB, (int)s1m[0][0]);
            int b10 = __builtin_amdgcn_ds_bpermute(idxB, (int)s1m[1][0]);
            int b01 = __builtin_amdgcn_ds_bpermute(idxB, (int)s1m[0][1]);
            int b11 = __builtin_amdgcn_ds_bpermute(idxB, (int)s1m[1][1]);
            U1[0] = (unsigned)(loHalf ? a00 : a10);
            U1[1] = (unsigned)(loHalf ? a01 : a11);
            U1[2] = (unsigned)(loHalf ? b00 : b10);
            U1[3] = (unsigned)(loHalf ? b01 : b11);
        }
        {
            int a00 = __builtin_amdgcn_ds_bpermute(idxA, (int)s2m[0][0]);
            int a10 = __builtin_amdgcn_ds_bpermute(idxA, (int)s2m[1][0]);
            int a01 = __builtin_amdgcn_ds_bpermute(idxA, (int)s2m[0][1]);
            int a11 = __builtin_amdgcn_ds_bpermute(idxA, (int)s2m[1][1]);
            int b00 = __builtin_amdgcn_ds_bpermute(idxB, (int)s2m[0][0]);
            int b10 = __builtin_amdgcn_ds_bpermute(idxB, (int)s2m[1][0]);
            int b01 = __builtin_amdgcn_ds_bpermute(idxB, (int)s2m[0][1]);
            int b11 = __builtin_amdgcn_ds_bpermute(idxB, (int)s2m[1][1]);
            U2[0] = (unsigned)(loHalf ? a00 : a10);
            U2[1] = (unsigned)(loHalf ? a01 : a11);
            U2[2] = (unsigned)(loHalf ? b00 : b10);
            U2[3] = (unsigned)(loHalf ? b01 : b11);
        }
        pa1o = __builtin_bit_cast(bf16x8, U1);
        pa2o = __builtin_bit_cast(bf16x8, U2);
    };

    int NI = g + 1;
    for (int i = 0; i < NI; ++i) {
        // own stage(i) loads done, then block-wide visibility via barrier
        asm volatile("s_waitcnt vmcnt(0)\n\ts_barrier" ::: "memory");
        const char* kbA = (const char*)Kring + (i & 1) * 16384;
        const char* kbB = kbA + 8192;

        // V loads FIRST (vfA then vfB), then K-stage(i+1): PV-A's implicit
        // wait is vmcnt(12), PV-B's vmcnt(4); stage drains only at next top.
        bf16x8 vfA[8], vfB[8];
        #pragma unroll
        for (int ec = 0; ec < 8; ++ec)
            vfA[ec] = *(const bf16x8*)(VtB + vgo[ec] + (2 * i) * 32);
        #pragma unroll
        for (int ec = 0; ec < 8; ++ec)
            vfB[ec] = *(const bf16x8*)(VtB + vgo[ec] + (2 * i + 1) * 32);
        if (i + 1 < NI) stage(i + 1, (i + 1) & 1);

        // K reads (both subtiles) from LDS
        bf16x8 kfA[2][4], kfB[2][4];
        #pragma unroll
        for (int c = 0; c < 2; ++c)
            #pragma unroll
            for (int j = 0; j < 4; ++j) {
                kfA[c][j] = *(const bf16x8*)(kbA + kfo[c][j]);
                kfB[c][j] = *(const bf16x8*)(kbB + kfo[c][j]);
            }

        // QK^T (swapped) for both subtiles: 8 independent 2-MFMA chains
        f32x4 S1A[2], S2A[2], S1B[2], S2B[2];
        #pragma unroll
        for (int c = 0; c < 2; ++c) {
            S1A[c] = zero4; S2A[c] = zero4; S1B[c] = zero4; S2B[c] = zero4;
        }
        #pragma unroll
        for (int c = 0; c < 2; ++c) {
            S1A[c] = __builtin_amdgcn_mfma_f32_16x16x32_bf16(kfA[c][0], q1a, S1A[c], 0, 0, 0);
            S1A[c] = __builtin_amdgcn_mfma_f32_16x16x32_bf16(kfA[c][1], q1b, S1A[c], 0, 0, 0);
            S2A[c] = __builtin_amdgcn_mfma_f32_16x16x32_bf16(kfA[c][2], q2a, S2A[c], 0, 0, 0);
            S2A[c] = __builtin_amdgcn_mfma_f32_16x16x32_bf16(kfA[c][3], q2b, S2A[c], 0, 0, 0);
            S1B[c] = __builtin_amdgcn_mfma_f32_16x16x32_bf16(kfB[c][0], q1a, S1B[c], 0, 0, 0);
            S1B[c] = __builtin_amdgcn_mfma_f32_16x16x32_bf16(kfB[c][1], q1b, S1B[c], 0, 0, 0);
            S2B[c] = __builtin_amdgcn_mfma_f32_16x16x32_bf16(kfB[c][2], q2a, S2B[c], 0, 0, 0);
            S2B[c] = __builtin_amdgcn_mfma_f32_16x16x32_bf16(kfB[c][3], q2b, S2B[c], 0, 0, 0);
        }

        bf16x8 pa1A, pa2A, pa1B, pa2B;
        transform(S1A, S2A, 2 * i, pa1A, pa2A);
        transform(S1B, S2B, 2 * i + 1, pa1B, pa2B);

        #pragma unroll
        for (int ec = 0; ec < 8; ++ec) {
            O1[ec] = __builtin_amdgcn_mfma_f32_16x16x32_bf16(pa1A, vfA[ec], O1[ec], 0, 0, 0);
            O2[ec] = __builtin_amdgcn_mfma_f32_16x16x32_bf16(pa2A, vfA[ec], O2[ec], 0, 0, 0);
        }
        #pragma unroll
        for (int ec = 0; ec < 8; ++ec) {
            O1[ec] = __builtin_amdgcn_mfma_f32_16x16x32_bf16(pa1B, vfB[ec], O1[ec], 0, 0, 0);
            O2[ec] = __builtin_amdgcn_mfma_f32_16x16x32_bf16(pa2B, vfB[ec], O2[ec], 0, 0, 0);
        }
    }

    // l sums: lane holds partial for row cl over its key-groups; reduce
    // across qd groups, then redistribute to output rows qd*4+r.
    l1s += __shfl_xor(l1s, 16); l1s += __shfl_xor(l1s, 32);
    l2s += __shfl_xor(l2s, 16); l2s += __shfl_xor(l2s, 32);
    float w1[4], w2[4];
    #pragma unroll
    for (int r = 0; r < 4; ++r) {
        float d1 = __shfl(l1s, qd * 4 + r);
        float d2 = __shfl(l2s, qd * 4 + r);
        w1[r] = 1.0f / d1;
        w2[r] = lamv / d2;
    }
    #pragma unroll
    for (int ec = 0; ec < 8; ++ec) {
        #pragma unroll
        for (int r = 0; r < 4; ++r) {
            size_t row = (size_t)(b * Tc + qrow + qd * 4 + r);
            attn[row * HVD + h * VDc + ec * 16 + cl] =
                f2bf(O1[ec][r] * w1[r] - O2[ec][r] * w2[r]);
        }
    }
}

// ---------------------------------------------------------------------------
// Fused row-stats + LayerNorm*0.2, in-place on bf16 attn. 128 thr/row.
// ---------------------------------------------------------------------------
__global__ __launch_bounds__(128) void ln_inplace(
    unsigned short* __restrict__ attn,
    const float* __restrict__ gnw, const float* __restrict__ gnb)
{
    int row = blockIdx.x, tid = threadIdx.x;
    unsigned short* p = attn + (size_t)row * HVD;
    float v[12];
    float s = 0.f, sq = 0.f;
    #pragma unroll
    for (int j = 0; j < 3; ++j) {
        int g = tid + j * 128;
        ushort4 u = *(const ushort4*)(p + g * 4);
        float x0 = bf2f(u.x), x1 = bf2f(u.y), x2 = bf2f(u.z), x3 = bf2f(u.w);
        v[j * 4 + 0] = x0; v[j * 4 + 1] = x1; v[j * 4 + 2] = x2; v[j * 4 + 3] = x3;
        s += x0 + x1 + x2 + x3;
        sq = fmaf(x0, x0, sq); sq = fmaf(x1, x1, sq);
        sq = fmaf(x2, x2, sq); sq = fmaf(x3, x3, sq);
    }
    #pragma unroll
    for (int off = 32; off; off >>= 1) { s += __shfl_xor(s, off); sq += __shfl_xor(sq, off); }
    __shared__ float ss[2], sqs[2];
    if ((tid & 63) == 0) { ss[tid >> 6] = s; sqs[tid >> 6] = sq; }
    __syncthreads();
    float S = ss[0] + ss[1], Q = sqs[0] + sqs[1];
    float mu = S * (1.0f / HVD);
    float rstd = rsqrtf(Q * (1.0f / HVD) - mu * mu + 1e-5f);
    #pragma unroll
    for (int j = 0; j < 3; ++j) {
        int g = tid + j * 128;
        float4 gw = *(const float4*)(gnw + g * 4);
        float4 gb = *(const float4*)(gnb + g * 4);
        ushort4 o;
        o.x = f2bf(((v[j * 4 + 0] - mu) * rstd * gw.x + gb.x) * 0.2f);
        o.y = f2bf(((v[j * 4 + 1] - mu) * rstd * gw.y + gb.y) * 0.2f);
        o.z = f2bf(((v[j * 4 + 2] - mu) * rstd * gw.z + gb.z) * 0.2f);
        o.w = f2bf(((v[j * 4 + 3] - mu) * rstd * gw.w + gb.w) * 0.2f);
        *(ushort4*)(p + g * 4) = o;
    }
}

// ---------------------------------------------------------------------------
// launch
// ---------------------------------------------------------------------------
extern "C" void kernel_launch(void* const* d_in, const int* in_sizes, int n_in,
                              void* d_out, int out_size, void* d_ws, size_t ws_size,
                              hipStream_t stream)
{
    const float* x   = (const float*)d_in[0];
    const float* Wq1 = (const float*)d_in[1];
    const float* Wk1 = (const float*)d_in[2];
    const float* Wq2 = (const float*)d_in[3];
    const float* Wk2 = (const float*)d_in[4];
    const float* Wv  = (const float*)d_in[5];
    const float* lq1 = (const float*)d_in[6];
    const float* lk1 = (const float*)d_in[7];
    const float* lq2 = (const float*)d_in[8];
    const float* lk2 = (const float*)d_in[9];
    const float* gnw = (const float*)d_in[10];
    const float* gnb = (const float*)d_in[11];
    const float* Wp  = (const float*)d_in[12];
    const float* bp  = (const float*)d_in[13];
    const int*   lidx = (const int*)d_in[14];
    float* out = (float*)d_out;

    // workspace layout (bytes):
    // WcatT bf16 [4608][768]:  7,077,888 @ 0
    // Xb    bf16 [4096][768]:  6,291,456 @ 7,077,888
    // Y     bf16 [4096][3072]: 25,165,824 @ 13,369,344
    // Vt    bf16 [48][128][1024]: 12,582,912 @ 38,535,168
    // attn  bf16 [4096][1536]: 12,582,912 @ 51,118,080
    // Wpb   bf16 [768][1536]:   2,359,296 @ 63,700,992
    // lam   f32 [12]                       @ 66,060,288
    char* w = (char*)d_ws;
    unsigned short* WcatT = (unsigned short*)(w);
    unsigned short* Xb    = (unsigned short*)(w + 7077888);
    unsigned short* Y     = (unsigned short*)(w + 13369344);
    unsigned short* VtW   = (unsigned short*)(w + 38535168);
    unsigned short* attn  = (unsigned short*)(w + 51118080);
    unsigned short* Wpb   = (unsigned short*)(w + 63700992);
    float* lam            = (float*)(w + 66060288);

    // fused casts + lambda + out zero-init + weight transpose (one launch)
    prep<<<dim3(8172), 256, 0, stream>>>(x, Wp, lq1, lk1, lq2, lk2, lidx,
                                         Wq1, Wk1, Wq2, Wk2, Wv,
                                         Xb, Wpb, lam, out, WcatT);
    // QKV: [4096,768] x [768,4608]; Q/K -> Y (LD 3072), V -> Vt transposed
    gemm_mfma<4, 768, YLD, false, true, 1><<<dim3(1152), 256, 0, stream>>>(
        Xb, WcatT, Y, nullptr, nullptr, VtW);
    // bh fastest (XCD pin); y -> g = 15-y; 768 blocks x 4 waves, K-only
    // 32KB LDS ring (3 blocks/CU), direct V loads
    diff_attn_mfma<<<dim3(Bc * Hc, 16), 256, 0, stream>>>(Y, VtW, lam, attn);
    ln_inplace<<<dim3(NROWS), 128, 0, stream>>>(attn, gnw, gnb);
    // OUT: [4096,1536] x [1536,768] -> out fp32 via split-K2 atomicAdd
    gemm_mfma<2, HVD, Cc, true, false, 2><<<dim3(768), 256, 0, stream>>>(
        attn, Wpb, nullptr, out, bp, nullptr);
}

// Round 15
// 235.881 us; speedup vs baseline: 1.1859x; 1.1859x over previous
//
#include <hip/hip_runtime.h>
#include <hip/hip_bf16.h>

// Problem constants
#define Bc   4
#define Tc   1024
#define Cc   768
#define Hc   12
#define HSc  64
#define VDc  128
#define NQKV 4608   // gemm N for qkv (4*768 Q/K + 1536 V)
#define YLD  3072   // Y row stride: Q/K only (V goes to Vt)
#define NROWS 4096  // B*T
#define HVD  1536   // H*VD

// Y (qk) column offsets
#define Q1OFF 0
#define K1OFF 768
#define Q2OFF 1536
#define K2OFF 2304

typedef __bf16 bf16x8 __attribute__((ext_vector_type(8)));
typedef float f32x4 __attribute__((ext_vector_type(4)));
typedef unsigned int u32x4 __attribute__((ext_vector_type(4)));

// exp(s*0.125) == exp2(s * 0.125*log2(e))
#define EXP2SCALE 0.18033688011112042f

static __device__ __forceinline__ float bf2f(unsigned short s) {
    return __uint_as_float(((unsigned int)s) << 16);
}
static __device__ __forceinline__ unsigned short f2bf(float f) {
    unsigned int u = __float_as_uint(f);
    unsigned int r = (u + 0x7FFFu + ((u >> 16) & 1u)) >> 16;  // round-nearest-even
    return (unsigned short)r;
}
static __device__ __forceinline__ unsigned int pack2bf(float lo, float hi) {
    // bf16(lo) | bf16(hi)<<16, half-up rounding (values >= 0)
    unsigned int a = (__float_as_uint(lo) + 0x8000u) >> 16;
    unsigned int b = (__float_as_uint(hi) + 0x8000u) & 0xFFFF0000u;
    return a | b;
}
// raw v_exp_f32: 2^x without libm denorm guards (inputs bounded here)
static __device__ __forceinline__ float fast_exp2(float x) {
    float r;
    asm("v_exp_f32 %0, %1" : "=v"(r) : "v"(x));
    return r;
}

// async global->LDS 16B per lane; lds base must be wave-uniform
static __device__ __forceinline__ void load16_lds(const void* g, void* l) {
    __builtin_amdgcn_global_load_lds(
        (const __attribute__((address_space(1))) void*)g,
        (__attribute__((address_space(3))) void*)l, 16, 0, 0);
}

// ---------------------------------------------------------------------------
// prep: fused cast x->bf16 (blocks 0..3071), cast Wp->bf16 (3072..4223),
// lambda (4224..4235), zero-init out fp32 (4236..7307, for split-K atomics),
// trans_w weight transpose-repack (7308..8171).
// ---------------------------------------------------------------------------
__global__ __launch_bounds__(256) void prep(
    const float* __restrict__ x, const float* __restrict__ Wp,
    const float* __restrict__ lq1, const float* __restrict__ lk1,
    const float* __restrict__ lq2, const float* __restrict__ lk2,
    const int* __restrict__ layer_idx,
    const float* __restrict__ Wq1, const float* __restrict__ Wk1,
    const float* __restrict__ Wq2, const float* __restrict__ Wk2,
    const float* __restrict__ Wv,
    unsigned short* __restrict__ Xb, unsigned short* __restrict__ Wpb,
    float* __restrict__ lam, float* __restrict__ outz,
    unsigned short* __restrict__ WcatT)
{
    __shared__ float tile[64][65];
    int bid = blockIdx.x, tid = threadIdx.x;
    if (bid < 3072) {
        size_t i = (size_t)bid * 256 + tid;
        float4 v = *(const float4*)(x + i * 4);
        ushort4 u;
        u.x = f2bf(v.x); u.y = f2bf(v.y); u.z = f2bf(v.z); u.w = f2bf(v.w);
        *(ushort4*)(Xb + i * 4) = u;
    } else if (bid < 4224) {
        size_t i = (size_t)(bid - 3072) * 256 + tid;
        float4 v = *(const float4*)(Wp + i * 4);
        ushort4 u;
        u.x = f2bf(v.x); u.y = f2bf(v.y); u.z = f2bf(v.z); u.w = f2bf(v.w);
        *(ushort4*)(Wpb + i * 4) = u;
    } else if (bid < 4236) {
        if (tid < 64) {
            int h = bid - 4224, l = tid;
            float li = (float)layer_idx[0];
            float dyn = 0.8f - 0.6f * expf(-0.3f * (li - 1.0f));
            int i = h * HSc + l;
            float v = expf(lq1[i] * lk1[i]) - expf(lq2[i] * lk2[i]) + dyn;
            #pragma unroll
            for (int off = 32; off; off >>= 1) v += __shfl_xor(v, off);
            if (l == 0) lam[h] = v * (1.0f / 64.0f);
        }
    } else if (bid < 7308) {
        size_t i = (size_t)(bid - 4236) * 256 + tid;
        float4 z = {0.f, 0.f, 0.f, 0.f};
        *(float4*)(outz + i * 4) = z;
    } else {
        // trans_w: repack 5 projection weights into WcatT[n][k], k-contig
        int t = bid - 7308;
        int kt = t % 12, nt = t / 12;
        int k0 = kt * 64, n0 = nt * 64;
        const float* src;
        int stride;
        if (n0 < 3072) {
            int which = n0 / 768, m = n0 - which * 768, h = m >> 6;
            const float* W = (which == 0) ? Wq1 : (which == 1) ? Wk1 : (which == 2) ? Wq2 : Wk2;
            src = W + ((size_t)h * 768 + k0) * 64;
            stride = 64;
        } else {
            int rel = n0 - 3072, h = rel >> 7, e0 = rel & 127;
            src = Wv + ((size_t)h * 768 + k0) * 128 + e0;
            stride = 128;
        }
        for (int i = tid; i < 4096; i += 256) {
            int kl = i >> 6, dl = i & 63;
            tile[dl][kl] = src[(size_t)kl * stride + dl];
        }
        __syncthreads();
        for (int i = tid; i < 4096; i += 256) {
            int nl = i >> 6, kl = i & 63;
            WcatT[(size_t)(n0 + nl) * 768 + k0 + kl] = f2bf(tile[nl][kl]);
        }
    }
}

// ---------------------------------------------------------------------------
// MFMA GEMM — R18 (frozen): ring pipeline + XCD-chunked swizzle + split-K.
// ---------------------------------------------------------------------------
template<int TN, int KD, int LDC, bool OUT_BIAS, bool SPLITV, int KSPLIT>
__global__ __launch_bounds__(256) void gemm_mfma(
    const unsigned short* __restrict__ A, const unsigned short* __restrict__ Bt,
    unsigned short* __restrict__ Cb, float* __restrict__ Cf,
    const float* __restrict__ bias, unsigned short* __restrict__ VtOut)
{
    constexpr int BN = TN * 32;
    constexpr int JB = TN / 2;
    constexpr int ASLOT = 128 * 64;           // ushorts: A halves (2x4096)
    constexpr int SLOT  = ASLOT + BN * 64;    // + B halves
    __shared__ unsigned short ring[2 * SLOT];
    int tid = threadIdx.x, lane = tid & 63, w = tid >> 6;
    int wm = w >> 1, wn = w & 1;

    // XCD-chunked swizzle decode
    int bid = blockIdx.x;
    int xcd = bid & 7;
    int idx = bid >> 3;
    int ks = 0;
    if (KSPLIT == 2) { ks = idx & 1; idx >>= 1; }
    int mi  = idx & 3;
    int ni  = idx >> 2;
    int m0 = (xcd * 4 + mi) * 128;
    int n0 = ni * BN;
    constexpr int KLOC = KD / KSPLIT;         // this block's K extent
    const int kBase = ks * KLOC;

    int lr = lane >> 2, lq = lane & 3;
    const unsigned short* gA[2];
    const unsigned short* gB[JB];
    #pragma unroll
    for (int j = 0; j < 2; ++j) {
        int row = w * 32 + j * 16 + lr;
        int qg = lq ^ ((row >> 1) & 3);
        gA[j] = A + (size_t)(m0 + row) * KD + kBase + qg * 8;
    }
    #pragma unroll
    for (int j = 0; j < JB; ++j) {
        int row = w * (JB * 16) + j * 16 + lr;
        int qg = lq ^ ((row >> 1) & 3);
        gB[j] = Bt + (size_t)(n0 + row) * KD + kBase + qg * 8;
    }

    int rr = lane & 15, qd = lane >> 4;
    int aOff[4], bOff[TN];
    #pragma unroll
    for (int i = 0; i < 4; ++i) {
        int row = wm * 64 + i * 16 + rr;
        int qs = qd ^ ((row >> 1) & 3);
        aOff[i] = row * 32 + qs * 8;
    }
    #pragma unroll
    for (int t = 0; t < TN; ++t) {
        int row = wn * (TN * 16) + t * 16 + rr;
        int qs = qd ^ ((row >> 1) & 3);
        bOff[t] = row * 32 + qs * 8;
    }

    auto stageG = [&](int k, int slot) {
        unsigned short* s = ring + slot * SLOT;
        int k64 = k * 64;
        load16_lds(gA[0] + k64,      s + (w * 2 + 0) * 512);
        load16_lds(gA[1] + k64,      s + (w * 2 + 1) * 512);
        load16_lds(gA[0] + k64 + 32, s + 4096 + (w * 2 + 0) * 512);
        load16_lds(gA[1] + k64 + 32, s + 4096 + (w * 2 + 1) * 512);
        #pragma unroll
        for (int j = 0; j < JB; ++j) {
            load16_lds(gB[j] + k64,      s + ASLOT + (w * JB + j) * 512);
            load16_lds(gB[j] + k64 + 32, s + ASLOT + BN * 32 + (w * JB + j) * 512);
        }
    };

    f32x4 acc[4][TN];
    #pragma unroll
    for (int i = 0; i < 4; ++i)
        #pragma unroll
        for (int t = 0; t < TN; ++t) acc[i][t] = {0.f, 0.f, 0.f, 0.f};

    constexpr int NT = KLOC / 64;
    stageG(0, 0);
    for (int k = 0; k < NT; ++k) {
        asm volatile("s_waitcnt vmcnt(0)\n\ts_barrier" ::: "memory");
        const unsigned short* s = ring + (k & 1) * SLOT;
        if (k + 1 < NT) stageG(k + 1, (k + 1) & 1);

        bf16x8 af0[4], af1[4], bf0[TN], bf1[TN];
        #pragma unroll
        for (int i = 0; i < 4; ++i) {
            af0[i] = *(const bf16x8*)(s + aOff[i]);
            af1[i] = *(const bf16x8*)(s + 4096 + aOff[i]);
        }
        #pragma unroll
        for (int t = 0; t < TN; ++t) {
            bf0[t] = *(const bf16x8*)(s + ASLOT + bOff[t]);
            bf1[t] = *(const bf16x8*)(s + ASLOT + BN * 32 + bOff[t]);
        }
        #pragma unroll
        for (int i = 0; i < 4; ++i)
            #pragma unroll
            for (int t = 0; t < TN; ++t) {
                acc[i][t] = __builtin_amdgcn_mfma_f32_16x16x32_bf16(af0[i], bf0[t], acc[i][t], 0, 0, 0);
                acc[i][t] = __builtin_amdgcn_mfma_f32_16x16x32_bf16(af1[i], bf1[t], acc[i][t], 0, 0, 0);
            }
    }

    #pragma unroll
    for (int t = 0; t < TN; ++t) {
        int col = n0 + wn * (TN * 16) + t * 16 + rr;
        if (SPLITV && col >= 3072) {
            int rel = col - 3072, hh = rel >> 7, e = rel & 127;
            #pragma unroll
            for (int i = 0; i < 4; ++i) {
                int row0 = m0 + wm * 64 + i * 16 + qd * 4;
                int b = row0 >> 10, tt = row0 & 1023;
                ushort4 pk;
                pk.x = f2bf(acc[i][t][0]); pk.y = f2bf(acc[i][t][1]);
                pk.z = f2bf(acc[i][t][2]); pk.w = f2bf(acc[i][t][3]);
                *(ushort4*)&VtOut[(size_t)((b * Hc + hh) * 128 + e) * 1024 + tt] = pk;
            }
        } else if (KSPLIT == 2) {
            float bv = (OUT_BIAS && ks == 0) ? bias[col] : 0.f;
            #pragma unroll
            for (int i = 0; i < 4; ++i) {
                #pragma unroll
                for (int r = 0; r < 4; ++r) {
                    int row = m0 + wm * 64 + i * 16 + qd * 4 + r;
                    atomicAdd(&Cf[(size_t)row * LDC + col], acc[i][t][r] + bv);
                }
            }
        } else {
            float bv = OUT_BIAS ? bias[col] : 0.f;
            #pragma unroll
            for (int i = 0; i < 4; ++i) {
                #pragma unroll
                for (int r = 0; r < 4; ++r) {
                    int row = m0 + wm * 64 + i * 16 + qd * 4 + r;
                    if (OUT_BIAS)
                        Cf[(size_t)row * LDC + col] = acc[i][t][r] + bv;
                    else
                        Cb[(size_t)row * LDC + col] = f2bf(acc[i][t][r]);
                }
            }
        }
    }
}

// ---------------------------------------------------------------------------
// MFMA differential flash attention — R23: 32 Q-rows per wave (2 row-groups
// sharing K/V fragments). R22 re-proved K AND V staging are load-bearing
// (direct V -> L1-line saturation, 105us); R19 proved >2 waves/SIMD is
// VGPR-unreachable. Remaining lever = ILP per wave (R15's proven direction):
// two 16-row groups per wave reuse the same kf/vf registers -> 80 MFMAs and
// 4 independent transform chains per 64-key iteration (was 40/2) at
// IDENTICAL staging traffic and barrier count. Row groups are 32-aligned so
// both share every iteration (no 64-key tile straddles only one group).
// Block: 4 waves x 32 rows = 128 rows; grid (48,8) = 384 blocks, all
// resident (cap 512); longest-first order pairs long+short per CU (~LPT).
// VGPR ~225 expected (NO launch_bounds forcing — R19 lesson); tripwires:
// VGPR>256 (occupancy cliff) or WRITE_SIZE >> 12288 (spill) -> revert R20.
// Ring/staging/transform identical to R15/R20.
// ---------------------------------------------------------------------------
__global__ __launch_bounds__(256) void diff_attn_mfma(
    const unsigned short* __restrict__ Y, const unsigned short* __restrict__ Vt,
    const float* __restrict__ lam_buf, unsigned short* __restrict__ attn)
{
    __shared__ __align__(16) unsigned short KVring[2 * 16384];  // 64 KB

    int bh = blockIdx.x;                          // fastest dim -> XCD-pinned
    int b = bh / Hc, h = bh - b * Hc;
    int g = 7 - (int)blockIdx.y;                  // longest first
    int tid = threadIdx.x, lane = tid & 63, wv = tid >> 6;
    int cl = lane & 15, qd = lane >> 4;
    float lamv = lam_buf[h];
    size_t rowbase = (size_t)(b * Tc) * YLD;
    const int hq = h * HSc;
    const unsigned short* VtB = Vt + ((size_t)bh << 17);   // bh*128*1024
    const f32x4 zero4 = {0.f, 0.f, 0.f, 0.f};

    // ---- staging lane->global mapping (one 8-load set per wave) ----
    // wave0: K1+K2 of subtile A; wave1: K1+K2 of B; wave2: V of A; wave3: V of B
    int sub = wv & 1;
    int off8[8];
    int dstoff;
    if (wv < 2) {
        int ksrow = lane >> 3;                  // row within 8-row seg
        int ksch  = (lane & 7) ^ ksrow;         // stored global chunk (inv swizzle)
        #pragma unroll
        for (int j = 0; j < 8; ++j) {
            int moff = (j < 4) ? K1OFF : K2OFF;
            off8[j] = ((j & 3) * 8 + ksrow) * YLD + moff + hq + ksch * 8;
        }
        dstoff = 0;
    } else {
        int vsel = lane >> 2;                   // e within 16-row seg
        int vsch = (lane & 3) ^ ((vsel >> 1) & 3);
        #pragma unroll
        for (int s = 0; s < 8; ++s)
            off8[s] = (s * 16 + vsel) * 1024 + vsch * 8;
        dstoff = 8192;
    }

    auto stage = [&](int i, int slot) {
        int kt = 2 * i + sub;
        char* base = (char*)KVring + slot * 32768 + sub * 16384 + dstoff;
        const unsigned short* g0 = (wv < 2)
            ? (Y + rowbase + (size_t)(kt * 32) * YLD)
            : (VtB + kt * 32);
        #pragma unroll
        for (int j = 0; j < 8; ++j)
            load16_lds(g0 + off8[j], base + j * 1024);
    };

    // ---- fragment LDS byte offsets within a 16KB subtile (swizzled) ----
    int kfo[2][4], vfo[8];
    #pragma unroll
    for (int c = 0; c < 2; ++c) {
        int row = c * 16 + cl;
        #pragma unroll
        for (int j = 0; j < 4; ++j)
            kfo[c][j] = (j >> 1) * 4096 + row * 128 +
                        ((((j & 1) * 4 + qd) ^ (row & 7)) << 4);
    }
    #pragma unroll
    for (int ec = 0; ec < 8; ++ec) {
        int e = ec * 16 + cl;
        vfo[ec] = 8192 + e * 64 + ((qd ^ ((e >> 1) & 3)) << 4);
    }

    // P-transform bpermute indices (byte = srclane*4)
    int idxA = ((32 * (qd & 1)) + cl) * 4;
    int idxB = idxA + 64;
    bool loHalf = (qd < 2);

    // two 16-row groups per wave
    int qr0 = g * 128 + wv * 32;
    int qr1 = qr0 + 16;

    stage(0, 0);

    size_t qoff0 = rowbase + (size_t)(qr0 + cl) * YLD;
    bf16x8 q1a0 = *(const bf16x8*)(Y + qoff0 + Q1OFF + hq + qd * 8);
    bf16x8 q1b0 = *(const bf16x8*)(Y + qoff0 + Q1OFF + hq + 32 + qd * 8);
    bf16x8 q2a0 = *(const bf16x8*)(Y + qoff0 + Q2OFF + hq + qd * 8);
    bf16x8 q2b0 = *(const bf16x8*)(Y + qoff0 + Q2OFF + hq + 32 + qd * 8);
    size_t qoff1 = rowbase + (size_t)(qr1 + cl) * YLD;
    bf16x8 q1a1 = *(const bf16x8*)(Y + qoff1 + Q1OFF + hq + qd * 8);
    bf16x8 q1b1 = *(const bf16x8*)(Y + qoff1 + Q1OFF + hq + 32 + qd * 8);
    bf16x8 q2a1 = *(const bf16x8*)(Y + qoff1 + Q2OFF + hq + qd * 8);
    bf16x8 q2b1 = *(const bf16x8*)(Y + qoff1 + Q2OFF + hq + 32 + qd * 8);

    f32x4 O1g0[8], O2g0[8], O1g1[8], O2g1[8];
    #pragma unroll
    for (int ec = 0; ec < 8; ++ec) {
        O1g0[ec] = zero4; O2g0[ec] = zero4;
        O1g1[ec] = zero4; O2g1[ec] = zero4;
    }
    float l1s0 = 0.f, l2s0 = 0.f, l1s1 = 0.f, l2s1 = 0.f;

    // mask + exp + pack + cross-lane gather for one 32-key subtile / row group
    auto transform = [&](f32x4 S1[2], f32x4 S2[2], int kt, int qrowX,
                         float& l1s, float& l2s, bf16x8& pa1o, bf16x8& pa2o) {
        if (kt * 32 + 31 > qrowX) {
            #pragma unroll
            for (int c = 0; c < 2; ++c) {
                int lim = qrowX + cl - kt * 32 - c * 16 - qd * 4;
                #pragma unroll
                for (int r = 0; r < 4; ++r) {
                    if (r > lim) { S1[c][r] = -1e30f; S2[c][r] = -1e30f; }
                }
            }
        }
        float p1v[2][4], p2v[2][4];
        #pragma unroll
        for (int c = 0; c < 2; ++c) {
            #pragma unroll
            for (int r = 0; r < 4; ++r) {
                p1v[c][r] = fast_exp2(S1[c][r] * EXP2SCALE);
                p2v[c][r] = fast_exp2(S2[c][r] * EXP2SCALE);
                l1s += p1v[c][r];
                l2s += p2v[c][r];
            }
        }
        unsigned int s1m[2][2], s2m[2][2];
        #pragma unroll
        for (int c = 0; c < 2; ++c) {
            s1m[c][0] = pack2bf(p1v[c][0], p1v[c][1]);
            s1m[c][1] = pack2bf(p1v[c][2], p1v[c][3]);
            s2m[c][0] = pack2bf(p2v[c][0], p2v[c][1]);
            s2m[c][1] = pack2bf(p2v[c][2], p2v[c][3]);
        }
        u32x4 U1, U2;
        {
            int a00 = __builtin_amdgcn_ds_bpermute(idxA, (int)s1m[0][0]);
            int a10 = __builtin_amdgcn_ds_bpermute(idxA, (int)s1m[1][0]);
            int a01 = __builtin_amdgcn_ds_bpermute(idxA, (int)s1m[0][1]);
            int a11 = __builtin_amdgcn_ds_bpermute(idxA, (int)s1m[1][1]);
            int b00 = __builtin_amdgcn_ds_bpermute(idxB, (int)s1m[0][0]);
            int b10 = __builtin_amdgcn_ds_bpermute(idxB, (int)s1m[1][0]);
            int b01 = __builtin_amdgcn_ds_bpermute(idxB, (int)s1m[0][1]);
            int b11 = __builtin_amdgcn_ds_bpermute(idxB, (int)s1m[1][1]);
            U1[0] = (unsigned)(loHalf ? a00 : a10);
            U1[1] = (unsigned)(loHalf ? a01 : a11);
            U1[2] = (unsigned)(loHalf ? b00 : b10);
            U1[3] = (unsigned)(loHalf ? b01 : b11);
        }
        {
            int a00 = __builtin_amdgcn_ds_bpermute(idxA, (int)s2m[0][0]);
            int a10 = __builtin_amdgcn_ds_bpermute(idxA, (int)s2m[1][0]);
            int a01 = __builtin_amdgcn_ds_bpermute(idxA, (int)s2m[0][1]);
            int a11 = __builtin_amdgcn_ds_bpermute(idxA, (int)s2m[1][1]);
            int b00 = __builtin_amdgcn_ds_bpermute(idxB, (int)s2m[0][0]);
            int b10 = __builtin_amdgcn_ds_bpermute(idxB, (int)s2m[1][0]);
            int b01 = __builtin_amdgcn_ds_bpermute(idxB, (int)s2m[0][1]);
            int b11 = __builtin_amdgcn_ds_bpermute(idxB, (int)s2m[1][1]);
            U2[0] = (unsigned)(loHalf ? a00 : a10);
            U2[1] = (unsigned)(loHalf ? a01 : a11);
            U2[2] = (unsigned)(loHalf ? b00 : b10);
            U2[3] = (unsigned)(loHalf ? b01 : b11);
        }
        pa1o = __builtin_bit_cast(bf16x8, U1);
        pa2o = __builtin_bit_cast(bf16x8, U2);
    };

    int NI = 2 * g + 2;
    for (int i = 0; i < NI; ++i) {
        // own stage(i) loads done, then block-wide visibility via barrier
        asm volatile("s_waitcnt vmcnt(0)\n\ts_barrier" ::: "memory");
        const char* kbA = (const char*)KVring + (i & 1) * 32768;
        const char* kbB = kbA + 16384;
        // prefetch next pair into the other slot (read 2 barriers ago)
        if (i + 1 < NI) stage(i + 1, (i + 1) & 1);

        // skip fully-masked iterations for this wave's rows (32-aligned
        // groups -> both groups share the skip); all waves hit the barrier
        if (i * 64 <= qr1 + 15) {
            // K reads (both key subtiles) + V-A reads
            bf16x8 kfA[2][4], kfB[2][4];
            #pragma unroll
            for (int c = 0; c < 2; ++c)
                #pragma unroll
                for (int j = 0; j < 4; ++j) {
                    kfA[c][j] = *(const bf16x8*)(kbA + kfo[c][j]);
                    kfB[c][j] = *(const bf16x8*)(kbB + kfo[c][j]);
                }
            bf16x8 vfA[8];
            #pragma unroll
            for (int ec = 0; ec < 8; ++ec)
                vfA[ec] = *(const bf16x8*)(kbA + vfo[ec]);

            // QK^T (swapped) for both key subtiles x both row groups
            f32x4 S1A0[2], S2A0[2], S1B0[2], S2B0[2];
            f32x4 S1A1[2], S2A1[2], S1B1[2], S2B1[2];
            #pragma unroll
            for (int c = 0; c < 2; ++c) {
                S1A0[c] = zero4; S2A0[c] = zero4; S1B0[c] = zero4; S2B0[c] = zero4;
                S1A1[c] = zero4; S2A1[c] = zero4; S1B1[c] = zero4; S2B1[c] = zero4;
            }
            #pragma unroll
            for (int c = 0; c < 2; ++c) {
                S1A0[c] = __builtin_amdgcn_mfma_f32_16x16x32_bf16(kfA[c][0], q1a0, S1A0[c], 0, 0, 0);
                S1A0[c] = __builtin_amdgcn_mfma_f32_16x16x32_bf16(kfA[c][1], q1b0, S1A0[c], 0, 0, 0);
                S2A0[c] = __builtin_amdgcn_mfma_f32_16x16x32_bf16(kfA[c][2], q2a0, S2A0[c], 0, 0, 0);
                S2A0[c] = __builtin_amdgcn_mfma_f32_16x16x32_bf16(kfA[c][3], q2b0, S2A0[c], 0, 0, 0);
                S1A1[c] = __builtin_amdgcn_mfma_f32_16x16x32_bf16(kfA[c][0], q1a1, S1A1[c], 0, 0, 0);
                S1A1[c] = __builtin_amdgcn_mfma_f32_16x16x32_bf16(kfA[c][1], q1b1, S1A1[c], 0, 0, 0);
                S2A1[c] = __builtin_amdgcn_mfma_f32_16x16x32_bf16(kfA[c][2], q2a1, S2A1[c], 0, 0, 0);
                S2A1[c] = __builtin_amdgcn_mfma_f32_16x16x32_bf16(kfA[c][3], q2b1, S2A1[c], 0, 0, 0);
                S1B0[c] = __builtin_amdgcn_mfma_f32_16x16x32_bf16(kfB[c][0], q1a0, S1B0[c], 0, 0, 0);
                S1B0[c] = __builtin_amdgcn_mfma_f32_16x16x32_bf16(kfB[c][1], q1b0, S1B0[c], 0, 0, 0);
                S2B0[c] = __builtin_amdgcn_mfma_f32_16x16x32_bf16(kfB[c][2], q2a0, S2B0[c], 0, 0, 0);
                S2B0[c] = __builtin_amdgcn_mfma_f32_16x16x32_bf16(kfB[c][3], q2b0, S2B0[c], 0, 0, 0);
                S1B1[c] = __builtin_amdgcn_mfma_f32_16x16x32_bf16(kfB[c][0], q1a1, S1B1[c], 0, 0, 0);
                S1B1[c] = __builtin_amdgcn_mfma_f32_16x16x32_bf16(kfB[c][1], q1b1, S1B1[c], 0, 0, 0);
                S2B1[c] = __builtin_amdgcn_mfma_f32_16x16x32_bf16(kfB[c][2], q2a1, S2B1[c], 0, 0, 0);
                S2B1[c] = __builtin_amdgcn_mfma_f32_16x16x32_bf16(kfB[c][3], q2b1, S2B1[c], 0, 0, 0);
            }

            bf16x8 pa1A0, pa2A0, pa1A1, pa2A1, pa1B0, pa2B0, pa1B1, pa2B1;
            transform(S1A0, S2A0, 2 * i, qr0, l1s0, l2s0, pa1A0, pa2A0);
            transform(S1A1, S2A1, 2 * i, qr1, l1s1, l2s1, pa1A1, pa2A1);
            // V-B reads queue BEHIND the ks0 bperms, ahead of ks1 bperms
            bf16x8 vfB[8];
            #pragma unroll
            for (int ec = 0; ec < 8; ++ec)
                vfB[ec] = *(const bf16x8*)(kbB + vfo[ec]);
            // PV for key-subtile A (both row groups)
            #pragma unroll
            for (int ec = 0; ec < 8; ++ec) {
                O1g0[ec] = __builtin_amdgcn_mfma_f32_16x16x32_bf16(pa1A0, vfA[ec], O1g0[ec], 0, 0, 0);
                O2g0[ec] = __builtin_amdgcn_mfma_f32_16x16x32_bf16(pa2A0, vfA[ec], O2g0[ec], 0, 0, 0);
            }
            #pragma unroll
            for (int ec = 0; ec < 8; ++ec) {
                O1g1[ec] = __builtin_amdgcn_mfma_f32_16x16x32_bf16(pa1A1, vfA[ec], O1g1[ec], 0, 0, 0);
                O2g1[ec] = __builtin_amdgcn_mfma_f32_16x16x32_bf16(pa2A1, vfA[ec], O2g1[ec], 0, 0, 0);
            }
            transform(S1B0, S2B0, 2 * i + 1, qr0, l1s0, l2s0, pa1B0, pa2B0);
            transform(S1B1, S2B1, 2 * i + 1, qr1, l1s1, l2s1, pa1B1, pa2B1);
            // PV for key-subtile B (both row groups)
            #pragma unroll
            for (int ec = 0; ec < 8; ++ec) {
                O1g0[ec] = __builtin_amdgcn_mfma_f32_16x16x32_bf16(pa1B0, vfB[ec], O1g0[ec], 0, 0, 0);
                O2g0[ec] = __builtin_amdgcn_mfma_f32_16x16x32_bf16(pa2B0, vfB[ec], O2g0[ec], 0, 0, 0);
            }
            #pragma unroll
            for (int ec = 0; ec < 8; ++ec) {
                O1g1[ec] = __builtin_amdgcn_mfma_f32_16x16x32_bf16(pa1B1, vfB[ec], O1g1[ec], 0, 0, 0);
                O2g1[ec] = __builtin_amdgcn_mfma_f32_16x16x32_bf16(pa2B1, vfB[ec], O2g1[ec], 0, 0, 0);
            }
        }
    }

    // l sums per row group; reduce across qd groups, redistribute to rows
    l1s0 += __shfl_xor(l1s0, 16); l1s0 += __shfl_xor(l1s0, 32);
    l2s0 += __shfl_xor(l2s0, 16); l2s0 += __shfl_xor(l2s0, 32);
    l1s1 += __shfl_xor(l1s1, 16); l1s1 += __shfl_xor(l1s1, 32);
    l2s1 += __shfl_xor(l2s1, 16); l2s1 += __shfl_xor(l2s1, 32);
    float w10[4], w20[4], w11[4], w21[4];
    #pragma unroll
    for (int r = 0; r < 4; ++r) {
        float d10 = __shfl(l1s0, qd * 4 + r);
        float d20 = __shfl(l2s0, qd * 4 + r);
        float d11 = __shfl(l1s1, qd * 4 + r);
        float d21 = __shfl(l2s1, qd * 4 + r);
        w10[r] = 1.0f / d10;
        w20[r] = lamv / d20;
        w11[r] = 1.0f / d11;
        w21[r] = lamv / d21;
    }
    #pragma unroll
    for (int ec = 0; ec < 8; ++ec) {
        #pragma unroll
        for (int r = 0; r < 4; ++r) {
            size_t row0 = (size_t)(b * Tc + qr0 + qd * 4 + r);
            attn[row0 * HVD + h * VDc + ec * 16 + cl] =
                f2bf(O1g0[ec][r] * w10[r] - O2g0[ec][r] * w20[r]);
            size_t row1 = (size_t)(b * Tc + qr1 + qd * 4 + r);
            attn[row1 * HVD + h * VDc + ec * 16 + cl] =
                f2bf(O1g1[ec][r] * w11[r] - O2g1[ec][r] * w21[r]);
        }
    }
}

// ---------------------------------------------------------------------------
// Fused row-stats + LayerNorm*0.2, in-place on bf16 attn. 128 thr/row.
// ---------------------------------------------------------------------------
__global__ __launch_bounds__(128) void ln_inplace(
    unsigned short* __restrict__ attn,
    const float* __restrict__ gnw, const float* __restrict__ gnb)
{
    int row = blockIdx.x, tid = threadIdx.x;
    unsigned short* p = attn + (size_t)row * HVD;
    float v[12];
    float s = 0.f, sq = 0.f;
    #pragma unroll
    for (int j = 0; j < 3; ++j) {
        int g = tid + j * 128;
        ushort4 u = *(const ushort4*)(p + g * 4);
        float x0 = bf2f(u.x), x1 = bf2f(u.y), x2 = bf2f(u.z), x3 = bf2f(u.w);
        v[j * 4 + 0] = x0; v[j * 4 + 1] = x1; v[j * 4 + 2] = x2; v[j * 4 + 3] = x3;
        s += x0 + x1 + x2 + x3;
        sq = fmaf(x0, x0, sq); sq = fmaf(x1, x1, sq);
        sq = fmaf(x2, x2, sq); sq = fmaf(x3, x3, sq);
    }
    #pragma unroll
    for (int off = 32; off; off >>= 1) { s += __shfl_xor(s, off); sq += __shfl_xor(sq, off); }
    __shared__ float ss[2], sqs[2];
    if ((tid & 63) == 0) { ss[tid >> 6] = s; sqs[tid >> 6] = sq; }
    __syncthreads();
    float S = ss[0] + ss[1], Q = sqs[0] + sqs[1];
    float mu = S * (1.0f / HVD);
    float rstd = rsqrtf(Q * (1.0f / HVD) - mu * mu + 1e-5f);
    #pragma unroll
    for (int j = 0; j < 3; ++j) {
        int g = tid + j * 128;
        float4 gw = *(const float4*)(gnw + g * 4);
        float4 gb = *(const float4*)(gnb + g * 4);
        ushort4 o;
        o.x = f2bf(((v[j * 4 + 0] - mu) * rstd * gw.x + gb.x) * 0.2f);
        o.y = f2bf(((v[j * 4 + 1] - mu) * rstd * gw.y + gb.y) * 0.2f);
        o.z = f2bf(((v[j * 4 + 2] - mu) * rstd * gw.z + gb.z) * 0.2f);
        o.w = f2bf(((v[j * 4 + 3] - mu) * rstd * gw.w + gb.w) * 0.2f);
        *(ushort4*)(p + g * 4) = o;
    }
}

// ---------------------------------------------------------------------------
// launch
// ---------------------------------------------------------------------------
extern "C" void kernel_launch(void* const* d_in, const int* in_sizes, int n_in,
                              void* d_out, int out_size, void* d_ws, size_t ws_size,
                              hipStream_t stream)
{
    const float* x   = (const float*)d_in[0];
    const float* Wq1 = (const float*)d_in[1];
    const float* Wk1 = (const float*)d_in[2];
    const float* Wq2 = (const float*)d_in[3];
    const float* Wk2 = (const float*)d_in[4];
    const float* Wv  = (const float*)d_in[5];
    const float* lq1 = (const float*)d_in[6];
    const float* lk1 = (const float*)d_in[7];
    const float* lq2 = (const float*)d_in[8];
    const float* lk2 = (const float*)d_in[9];
    const float* gnw = (const float*)d_in[10];
    const float* gnb = (const float*)d_in[11];
    const float* Wp  = (const float*)d_in[12];
    const float* bp  = (const float*)d_in[13];
    const int*   lidx = (const int*)d_in[14];
    float* out = (float*)d_out;

    // workspace layout (bytes):
    // WcatT bf16 [4608][768]:  7,077,888 @ 0
    // Xb    bf16 [4096][768]:  6,291,456 @ 7,077,888
    // Y     bf16 [4096][3072]: 25,165,824 @ 13,369,344
    // Vt    bf16 [48][128][1024]: 12,582,912 @ 38,535,168
    // attn  bf16 [4096][1536]: 12,582,912 @ 51,118,080
    // Wpb   bf16 [768][1536]:   2,359,296 @ 63,700,992
    // lam   f32 [12]                       @ 66,060,288
    char* w = (char*)d_ws;
    unsigned short* WcatT = (unsigned short*)(w);
    unsigned short* Xb    = (unsigned short*)(w + 7077888);
    unsigned short* Y     = (unsigned short*)(w + 13369344);
    unsigned short* VtW   = (unsigned short*)(w + 38535168);
    unsigned short* attn  = (unsigned short*)(w + 51118080);
    unsigned short* Wpb   = (unsigned short*)(w + 63700992);
    float* lam            = (float*)(w + 66060288);

    // fused casts + lambda + out zero-init + weight transpose (one launch)
    prep<<<dim3(8172), 256, 0, stream>>>(x, Wp, lq1, lk1, lq2, lk2, lidx,
                                         Wq1, Wk1, Wq2, Wk2, Wv,
                                         Xb, Wpb, lam, out, WcatT);
    // QKV: [4096,768] x [768,4608]; Q/K -> Y (LD 3072), V -> Vt transposed
    gemm_mfma<4, 768, YLD, false, true, 1><<<dim3(1152), 256, 0, stream>>>(
        Xb, WcatT, Y, nullptr, nullptr, VtW);
    // bh fastest (XCD pin); y -> g = 7-y, longest-first; 384 blocks x 4 waves,
    // 32 rows/wave (128 rows/block), 64-key iterations, 2-slot 64KB ring
    diff_attn_mfma<<<dim3(Bc * Hc, 8), 256, 0, stream>>>(Y, VtW, lam, attn);
    ln_inplace<<<dim3(NROWS), 128, 0, stream>>>(attn, gnw, gnb);
    // OUT: [4096,1536] x [1536,768] -> out fp32 via split-K2 atomicAdd
    gemm_mfma<2, HVD, Cc, true, false, 2><<<dim3(768), 256, 0, stream>>>(
        attn, Wpb, nullptr, out, bp, nullptr);
}

// Round 16
// 234.148 us; speedup vs baseline: 1.1946x; 1.0074x over previous
//
#include <hip/hip_runtime.h>
#include <hip/hip_bf16.h>

// Problem constants
#define Bc   4
#define Tc   1024
#define Cc   768
#define Hc   12
#define HSc  64
#define VDc  128
#define NQKV 4608   // gemm N for qkv (4*768 Q/K + 1536 V)
#define YLD  3072   // Y row stride: Q/K only (V goes to Vt)
#define NROWS 4096  // B*T
#define HVD  1536   // H*VD

// Y (qk) column offsets
#define Q1OFF 0
#define K1OFF 768
#define Q2OFF 1536
#define K2OFF 2304

typedef __bf16 bf16x8 __attribute__((ext_vector_type(8)));
typedef float f32x4 __attribute__((ext_vector_type(4)));
typedef unsigned int u32x4 __attribute__((ext_vector_type(4)));

// exp(s*0.125) == exp2(s * 0.125*log2(e))
#define EXP2SCALE 0.18033688011112042f

static __device__ __forceinline__ float bf2f(unsigned short s) {
    return __uint_as_float(((unsigned int)s) << 16);
}
static __device__ __forceinline__ unsigned short f2bf(float f) {
    unsigned int u = __float_as_uint(f);
    unsigned int r = (u + 0x7FFFu + ((u >> 16) & 1u)) >> 16;  // round-nearest-even
    return (unsigned short)r;
}
static __device__ __forceinline__ unsigned int pack2bf(float lo, float hi) {
    // bf16(lo) | bf16(hi)<<16, half-up rounding (values >= 0)
    unsigned int a = (__float_as_uint(lo) + 0x8000u) >> 16;
    unsigned int b = (__float_as_uint(hi) + 0x8000u) & 0xFFFF0000u;
    return a | b;
}
// raw v_exp_f32: 2^x without libm denorm guards (inputs bounded here)
static __device__ __forceinline__ float fast_exp2(float x) {
    float r;
    asm("v_exp_f32 %0, %1" : "=v"(r) : "v"(x));
    return r;
}

// async global->LDS 16B per lane; lds base must be wave-uniform
static __device__ __forceinline__ void load16_lds(const void* g, void* l) {
    __builtin_amdgcn_global_load_lds(
        (const __attribute__((address_space(1))) void*)g,
        (__attribute__((address_space(3))) void*)l, 16, 0, 0);
}

// ---------------------------------------------------------------------------
// prep: fused cast x->bf16 (blocks 0..3071), cast Wp->bf16 (3072..4223),
// lambda (4224..4235), zero-init out fp32 (4236..7307, for split-K atomics),
// trans_w weight transpose-repack (7308..8171).
// ---------------------------------------------------------------------------
__global__ __launch_bounds__(256) void prep(
    const float* __restrict__ x, const float* __restrict__ Wp,
    const float* __restrict__ lq1, const float* __restrict__ lk1,
    const float* __restrict__ lq2, const float* __restrict__ lk2,
    const int* __restrict__ layer_idx,
    const float* __restrict__ Wq1, const float* __restrict__ Wk1,
    const float* __restrict__ Wq2, const float* __restrict__ Wk2,
    const float* __restrict__ Wv,
    unsigned short* __restrict__ Xb, unsigned short* __restrict__ Wpb,
    float* __restrict__ lam, float* __restrict__ outz,
    unsigned short* __restrict__ WcatT)
{
    __shared__ float tile[64][65];
    int bid = blockIdx.x, tid = threadIdx.x;
    if (bid < 3072) {
        size_t i = (size_t)bid * 256 + tid;
        float4 v = *(const float4*)(x + i * 4);
        ushort4 u;
        u.x = f2bf(v.x); u.y = f2bf(v.y); u.z = f2bf(v.z); u.w = f2bf(v.w);
        *(ushort4*)(Xb + i * 4) = u;
    } else if (bid < 4224) {
        size_t i = (size_t)(bid - 3072) * 256 + tid;
        float4 v = *(const float4*)(Wp + i * 4);
        ushort4 u;
        u.x = f2bf(v.x); u.y = f2bf(v.y); u.z = f2bf(v.z); u.w = f2bf(v.w);
        *(ushort4*)(Wpb + i * 4) = u;
    } else if (bid < 4236) {
        if (tid < 64) {
            int h = bid - 4224, l = tid;
            float li = (float)layer_idx[0];
            float dyn = 0.8f - 0.6f * expf(-0.3f * (li - 1.0f));
            int i = h * HSc + l;
            float v = expf(lq1[i] * lk1[i]) - expf(lq2[i] * lk2[i]) + dyn;
            #pragma unroll
            for (int off = 32; off; off >>= 1) v += __shfl_xor(v, off);
            if (l == 0) lam[h] = v * (1.0f / 64.0f);
        }
    } else if (bid < 7308) {
        size_t i = (size_t)(bid - 4236) * 256 + tid;
        float4 z = {0.f, 0.f, 0.f, 0.f};
        *(float4*)(outz + i * 4) = z;
    } else {
        // trans_w: repack 5 projection weights into WcatT[n][k], k-contig
        int t = bid - 7308;
        int kt = t % 12, nt = t / 12;
        int k0 = kt * 64, n0 = nt * 64;
        const float* src;
        int stride;
        if (n0 < 3072) {
            int which = n0 / 768, m = n0 - which * 768, h = m >> 6;
            const float* W = (which == 0) ? Wq1 : (which == 1) ? Wk1 : (which == 2) ? Wq2 : Wk2;
            src = W + ((size_t)h * 768 + k0) * 64;
            stride = 64;
        } else {
            int rel = n0 - 3072, h = rel >> 7, e0 = rel & 127;
            src = Wv + ((size_t)h * 768 + k0) * 128 + e0;
            stride = 128;
        }
        for (int i = tid; i < 4096; i += 256) {
            int kl = i >> 6, dl = i & 63;
            tile[dl][kl] = src[(size_t)kl * stride + dl];
        }
        __syncthreads();
        for (int i = tid; i < 4096; i += 256) {
            int nl = i >> 6, kl = i & 63;
            WcatT[(size_t)(n0 + nl) * 768 + k0 + kl] = f2bf(tile[nl][kl]);
        }
    }
}

// ---------------------------------------------------------------------------
// MFMA GEMM — R18 (frozen): ring pipeline + XCD-chunked swizzle + split-K.
// ---------------------------------------------------------------------------
template<int TN, int KD, int LDC, bool OUT_BIAS, bool SPLITV, int KSPLIT>
__global__ __launch_bounds__(256) void gemm_mfma(
    const unsigned short* __restrict__ A, const unsigned short* __restrict__ Bt,
    unsigned short* __restrict__ Cb, float* __restrict__ Cf,
    const float* __restrict__ bias, unsigned short* __restrict__ VtOut)
{
    constexpr int BN = TN * 32;
    constexpr int JB = TN / 2;
    constexpr int ASLOT = 128 * 64;           // ushorts: A halves (2x4096)
    constexpr int SLOT  = ASLOT + BN * 64;    // + B halves
    __shared__ unsigned short ring[2 * SLOT];
    int tid = threadIdx.x, lane = tid & 63, w = tid >> 6;
    int wm = w >> 1, wn = w & 1;

    // XCD-chunked swizzle decode
    int bid = blockIdx.x;
    int xcd = bid & 7;
    int idx = bid >> 3;
    int ks = 0;
    if (KSPLIT == 2) { ks = idx & 1; idx >>= 1; }
    int mi  = idx & 3;
    int ni  = idx >> 2;
    int m0 = (xcd * 4 + mi) * 128;
    int n0 = ni * BN;
    constexpr int KLOC = KD / KSPLIT;         // this block's K extent
    const int kBase = ks * KLOC;

    int lr = lane >> 2, lq = lane & 3;
    const unsigned short* gA[2];
    const unsigned short* gB[JB];
    #pragma unroll
    for (int j = 0; j < 2; ++j) {
        int row = w * 32 + j * 16 + lr;
        int qg = lq ^ ((row >> 1) & 3);
        gA[j] = A + (size_t)(m0 + row) * KD + kBase + qg * 8;
    }
    #pragma unroll
    for (int j = 0; j < JB; ++j) {
        int row = w * (JB * 16) + j * 16 + lr;
        int qg = lq ^ ((row >> 1) & 3);
        gB[j] = Bt + (size_t)(n0 + row) * KD + kBase + qg * 8;
    }

    int rr = lane & 15, qd = lane >> 4;
    int aOff[4], bOff[TN];
    #pragma unroll
    for (int i = 0; i < 4; ++i) {
        int row = wm * 64 + i * 16 + rr;
        int qs = qd ^ ((row >> 1) & 3);
        aOff[i] = row * 32 + qs * 8;
    }
    #pragma unroll
    for (int t = 0; t < TN; ++t) {
        int row = wn * (TN * 16) + t * 16 + rr;
        int qs = qd ^ ((row >> 1) & 3);
        bOff[t] = row * 32 + qs * 8;
    }

    auto stageG = [&](int k, int slot) {
        unsigned short* s = ring + slot * SLOT;
        int k64 = k * 64;
        load16_lds(gA[0] + k64,      s + (w * 2 + 0) * 512);
        load16_lds(gA[1] + k64,      s + (w * 2 + 1) * 512);
        load16_lds(gA[0] + k64 + 32, s + 4096 + (w * 2 + 0) * 512);
        load16_lds(gA[1] + k64 + 32, s + 4096 + (w * 2 + 1) * 512);
        #pragma unroll
        for (int j = 0; j < JB; ++j) {
            load16_lds(gB[j] + k64,      s + ASLOT + (w * JB + j) * 512);
            load16_lds(gB[j] + k64 + 32, s + ASLOT + BN * 32 + (w * JB + j) * 512);
        }
    };

    f32x4 acc[4][TN];
    #pragma unroll
    for (int i = 0; i < 4; ++i)
        #pragma unroll
        for (int t = 0; t < TN; ++t) acc[i][t] = {0.f, 0.f, 0.f, 0.f};

    constexpr int NT = KLOC / 64;
    stageG(0, 0);
    for (int k = 0; k < NT; ++k) {
        asm volatile("s_waitcnt vmcnt(0)\n\ts_barrier" ::: "memory");
        const unsigned short* s = ring + (k & 1) * SLOT;
        if (k + 1 < NT) stageG(k + 1, (k + 1) & 1);

        bf16x8 af0[4], af1[4], bf0[TN], bf1[TN];
        #pragma unroll
        for (int i = 0; i < 4; ++i) {
            af0[i] = *(const bf16x8*)(s + aOff[i]);
            af1[i] = *(const bf16x8*)(s + 4096 + aOff[i]);
        }
        #pragma unroll
        for (int t = 0; t < TN; ++t) {
            bf0[t] = *(const bf16x8*)(s + ASLOT + bOff[t]);
            bf1[t] = *(const bf16x8*)(s + ASLOT + BN * 32 + bOff[t]);
        }
        #pragma unroll
        for (int i = 0; i < 4; ++i)
            #pragma unroll
            for (int t = 0; t < TN; ++t) {
                acc[i][t] = __builtin_amdgcn_mfma_f32_16x16x32_bf16(af0[i], bf0[t], acc[i][t], 0, 0, 0);
                acc[i][t] = __builtin_amdgcn_mfma_f32_16x16x32_bf16(af1[i], bf1[t], acc[i][t], 0, 0, 0);
            }
    }

    #pragma unroll
    for (int t = 0; t < TN; ++t) {
        int col = n0 + wn * (TN * 16) + t * 16 + rr;
        if (SPLITV && col >= 3072) {
            int rel = col - 3072, hh = rel >> 7, e = rel & 127;
            #pragma unroll
            for (int i = 0; i < 4; ++i) {
                int row0 = m0 + wm * 64 + i * 16 + qd * 4;
                int b = row0 >> 10, tt = row0 & 1023;
                ushort4 pk;
                pk.x = f2bf(acc[i][t][0]); pk.y = f2bf(acc[i][t][1]);
                pk.z = f2bf(acc[i][t][2]); pk.w = f2bf(acc[i][t][3]);
                *(ushort4*)&VtOut[(size_t)((b * Hc + hh) * 128 + e) * 1024 + tt] = pk;
            }
        } else if (KSPLIT == 2) {
            float bv = (OUT_BIAS && ks == 0) ? bias[col] : 0.f;
            #pragma unroll
            for (int i = 0; i < 4; ++i) {
                #pragma unroll
                for (int r = 0; r < 4; ++r) {
                    int row = m0 + wm * 64 + i * 16 + qd * 4 + r;
                    atomicAdd(&Cf[(size_t)row * LDC + col], acc[i][t][r] + bv);
                }
            }
        } else {
            float bv = OUT_BIAS ? bias[col] : 0.f;
            #pragma unroll
            for (int i = 0; i < 4; ++i) {
                #pragma unroll
                for (int r = 0; r < 4; ++r) {
                    int row = m0 + wm * 64 + i * 16 + qd * 4 + r;
                    if (OUT_BIAS)
                        Cf[(size_t)row * LDC + col] = acc[i][t][r] + bv;
                    else
                        Cb[(size_t)row * LDC + col] = f2bf(acc[i][t][r]);
                }
            }
        }
    }
}

// ---------------------------------------------------------------------------
// MFMA differential flash attention — FINAL (R15/R20 structure, best
// measured: 61.5 us, VGPR 144, no spill). Session conclusions baked in:
// - 64-key iterations (2 indep QK->exp->bperm->PV chains): the ONE ILP win
//   (+45%, R15). Further ILP (32 rows/wave, R23) is NULL: the limiter is
//   the serial per-wave issue stream, which scales with work.
// - K AND V staging in the 64KB 2-slot ring are BOTH load-bearing (R22:
//   direct V loads -> L1-line saturation, 105us; R8/R11 same for K).
// - Occupancy walls: >2 waves/SIMD is VGPR-unreachable (R19: (512,4) ->
//   spill, 533MB scratch); smaller LDS costs more than it gains (R22).
// - Counted vmcnt + raw s_barrier + 1-deep prefetch (R13) ~2%; swapped
//   QK^T + bpermute transform (R14) ~2%; LPT longest-first + XCD pinning.
// ---------------------------------------------------------------------------
__global__ __launch_bounds__(256) void diff_attn_mfma(
    const unsigned short* __restrict__ Y, const unsigned short* __restrict__ Vt,
    const float* __restrict__ lam_buf, unsigned short* __restrict__ attn)
{
    __shared__ __align__(16) unsigned short KVring[2 * 16384];  // 64 KB

    int bh = blockIdx.x;                          // fastest dim -> XCD-pinned
    int b = bh / Hc, h = bh - b * Hc;
    int g = 15 - (int)blockIdx.y;                 // longest first
    int tid = threadIdx.x, lane = tid & 63, wv = tid >> 6;
    int cl = lane & 15, qd = lane >> 4;
    float lamv = lam_buf[h];
    size_t rowbase = (size_t)(b * Tc) * YLD;
    const int hq = h * HSc;
    const unsigned short* VtB = Vt + ((size_t)bh << 17);   // bh*128*1024
    const f32x4 zero4 = {0.f, 0.f, 0.f, 0.f};

    // ---- staging lane->global mapping (one 8-load set per wave) ----
    // wave0: K1+K2 of subtile A; wave1: K1+K2 of B; wave2: V of A; wave3: V of B
    int sub = wv & 1;
    int off8[8];
    int dstoff;
    if (wv < 2) {
        int ksrow = lane >> 3;                  // row within 8-row seg
        int ksch  = (lane & 7) ^ ksrow;         // stored global chunk (inv swizzle)
        #pragma unroll
        for (int j = 0; j < 8; ++j) {
            int moff = (j < 4) ? K1OFF : K2OFF;
            off8[j] = ((j & 3) * 8 + ksrow) * YLD + moff + hq + ksch * 8;
        }
        dstoff = 0;
    } else {
        int vsel = lane >> 2;                   // e within 16-row seg
        int vsch = (lane & 3) ^ ((vsel >> 1) & 3);
        #pragma unroll
        for (int s = 0; s < 8; ++s)
            off8[s] = (s * 16 + vsel) * 1024 + vsch * 8;
        dstoff = 8192;
    }

    auto stage = [&](int i, int slot) {
        int kt = 2 * i + sub;
        char* base = (char*)KVring + slot * 32768 + sub * 16384 + dstoff;
        const unsigned short* g0 = (wv < 2)
            ? (Y + rowbase + (size_t)(kt * 32) * YLD)
            : (VtB + kt * 32);
        #pragma unroll
        for (int j = 0; j < 8; ++j)
            load16_lds(g0 + off8[j], base + j * 1024);
    };

    // ---- fragment LDS byte offsets within a 16KB subtile (swizzled) ----
    int kfo[2][4], vfo[8];
    #pragma unroll
    for (int c = 0; c < 2; ++c) {
        int row = c * 16 + cl;
        #pragma unroll
        for (int j = 0; j < 4; ++j)
            kfo[c][j] = (j >> 1) * 4096 + row * 128 +
                        ((((j & 1) * 4 + qd) ^ (row & 7)) << 4);
    }
    #pragma unroll
    for (int ec = 0; ec < 8; ++ec) {
        int e = ec * 16 + cl;
        vfo[ec] = 8192 + e * 64 + ((qd ^ ((e >> 1) & 3)) << 4);
    }

    // P-transform bpermute indices (byte = srclane*4)
    int idxA = ((32 * (qd & 1)) + cl) * 4;
    int idxB = idxA + 64;
    bool loHalf = (qd < 2);

    int qrow = g * 64 + wv * 16;

    stage(0, 0);

    size_t qoff = rowbase + (size_t)(qrow + cl) * YLD;
    bf16x8 q1a = *(const bf16x8*)(Y + qoff + Q1OFF + hq + qd * 8);
    bf16x8 q1b = *(const bf16x8*)(Y + qoff + Q1OFF + hq + 32 + qd * 8);
    bf16x8 q2a = *(const bf16x8*)(Y + qoff + Q2OFF + hq + qd * 8);
    bf16x8 q2b = *(const bf16x8*)(Y + qoff + Q2OFF + hq + 32 + qd * 8);

    f32x4 O1[8], O2[8];
    #pragma unroll
    for (int ec = 0; ec < 8; ++ec) { O1[ec] = zero4; O2[ec] = zero4; }
    float l1s = 0.f, l2s = 0.f;

    // mask + exp + pack + cross-lane gather for one 32-key subtile
    auto transform = [&](f32x4 S1[2], f32x4 S2[2], int kt,
                         bf16x8& pa1o, bf16x8& pa2o) {
        if (kt * 32 + 31 > qrow) {
            #pragma unroll
            for (int c = 0; c < 2; ++c) {
                int lim = qrow + cl - kt * 32 - c * 16 - qd * 4;
                #pragma unroll
                for (int r = 0; r < 4; ++r) {
                    if (r > lim) { S1[c][r] = -1e30f; S2[c][r] = -1e30f; }
                }
            }
        }
        float p1v[2][4], p2v[2][4];
        #pragma unroll
        for (int c = 0; c < 2; ++c) {
            #pragma unroll
            for (int r = 0; r < 4; ++r) {
                p1v[c][r] = fast_exp2(S1[c][r] * EXP2SCALE);
                p2v[c][r] = fast_exp2(S2[c][r] * EXP2SCALE);
                l1s += p1v[c][r];
                l2s += p2v[c][r];
            }
        }
        unsigned int s1m[2][2], s2m[2][2];
        #pragma unroll
        for (int c = 0; c < 2; ++c) {
            s1m[c][0] = pack2bf(p1v[c][0], p1v[c][1]);
            s1m[c][1] = pack2bf(p1v[c][2], p1v[c][3]);
            s2m[c][0] = pack2bf(p2v[c][0], p2v[c][1]);
            s2m[c][1] = pack2bf(p2v[c][2], p2v[c][3]);
        }
        u32x4 U1, U2;
        {
            int a00 = __builtin_amdgcn_ds_bpermute(idxA, (int)s1m[0][0]);
            int a10 = __builtin_amdgcn_ds_bpermute(idxA, (int)s1m[1][0]);
            int a01 = __builtin_amdgcn_ds_bpermute(idxA, (int)s1m[0][1]);
            int a11 = __builtin_amdgcn_ds_bpermute(idxA, (int)s1m[1][1]);
            int b00 = __builtin_amdgcn_ds_bpermute(idxB, (int)s1m[0][0]);
            int b10 = __builtin_amdgcn_ds_bpermute(idxB, (int)s1m[1][0]);
            int b01 = __builtin_amdgcn_ds_bpermute(idxB, (int)s1m[0][1]);
            int b11 = __builtin_amdgcn_ds_bpermute(idxB, (int)s1m[1][1]);
            U1[0] = (unsigned)(loHalf ? a00 : a10);
            U1[1] = (unsigned)(loHalf ? a01 : a11);
            U1[2] = (unsigned)(loHalf ? b00 : b10);
            U1[3] = (unsigned)(loHalf ? b01 : b11);
        }
        {
            int a00 = __builtin_amdgcn_ds_bpermute(idxA, (int)s2m[0][0]);
            int a10 = __builtin_amdgcn_ds_bpermute(idxA, (int)s2m[1][0]);
            int a01 = __builtin_amdgcn_ds_bpermute(idxA, (int)s2m[0][1]);
            int a11 = __builtin_amdgcn_ds_bpermute(idxA, (int)s2m[1][1]);
            int b00 = __builtin_amdgcn_ds_bpermute(idxB, (int)s2m[0][0]);
            int b10 = __builtin_amdgcn_ds_bpermute(idxB, (int)s2m[1][0]);
            int b01 = __builtin_amdgcn_ds_bpermute(idxB, (int)s2m[0][1]);
            int b11 = __builtin_amdgcn_ds_bpermute(idxB, (int)s2m[1][1]);
            U2[0] = (unsigned)(loHalf ? a00 : a10);
            U2[1] = (unsigned)(loHalf ? a01 : a11);
            U2[2] = (unsigned)(loHalf ? b00 : b10);
            U2[3] = (unsigned)(loHalf ? b01 : b11);
        }
        pa1o = __builtin_bit_cast(bf16x8, U1);
        pa2o = __builtin_bit_cast(bf16x8, U2);
    };

    int NI = g + 1;
    for (int i = 0; i < NI; ++i) {
        // own stage(i) loads done, then block-wide visibility via barrier
        asm volatile("s_waitcnt vmcnt(0)\n\ts_barrier" ::: "memory");
        const char* kbA = (const char*)KVring + (i & 1) * 32768;
        const char* kbB = kbA + 16384;
        // prefetch next pair into the other slot (read 2 barriers ago)
        if (i + 1 < NI) stage(i + 1, (i + 1) & 1);

        // K reads (both subtiles) + V-A reads
        bf16x8 kfA[2][4], kfB[2][4];
        #pragma unroll
        for (int c = 0; c < 2; ++c)
            #pragma unroll
            for (int j = 0; j < 4; ++j) {
                kfA[c][j] = *(const bf16x8*)(kbA + kfo[c][j]);
                kfB[c][j] = *(const bf16x8*)(kbB + kfo[c][j]);
            }
        bf16x8 vfA[8];
        #pragma unroll
        for (int ec = 0; ec < 8; ++ec)
            vfA[ec] = *(const bf16x8*)(kbA + vfo[ec]);

        // QK^T (swapped) for both subtiles: 8 independent 2-MFMA chains
        f32x4 S1A[2], S2A[2], S1B[2], S2B[2];
        #pragma unroll
        for (int c = 0; c < 2; ++c) {
            S1A[c] = zero4; S2A[c] = zero4; S1B[c] = zero4; S2B[c] = zero4;
        }
        #pragma unroll
        for (int c = 0; c < 2; ++c) {
            S1A[c] = __builtin_amdgcn_mfma_f32_16x16x32_bf16(kfA[c][0], q1a, S1A[c], 0, 0, 0);
            S1A[c] = __builtin_amdgcn_mfma_f32_16x16x32_bf16(kfA[c][1], q1b, S1A[c], 0, 0, 0);
            S2A[c] = __builtin_amdgcn_mfma_f32_16x16x32_bf16(kfA[c][2], q2a, S2A[c], 0, 0, 0);
            S2A[c] = __builtin_amdgcn_mfma_f32_16x16x32_bf16(kfA[c][3], q2b, S2A[c], 0, 0, 0);
            S1B[c] = __builtin_amdgcn_mfma_f32_16x16x32_bf16(kfB[c][0], q1a, S1B[c], 0, 0, 0);
            S1B[c] = __builtin_amdgcn_mfma_f32_16x16x32_bf16(kfB[c][1], q1b, S1B[c], 0, 0, 0);
            S2B[c] = __builtin_amdgcn_mfma_f32_16x16x32_bf16(kfB[c][2], q2a, S2B[c], 0, 0, 0);
            S2B[c] = __builtin_amdgcn_mfma_f32_16x16x32_bf16(kfB[c][3], q2b, S2B[c], 0, 0, 0);
        }

        bf16x8 pa1A, pa2A, pa1B, pa2B;
        transform(S1A, S2A, 2 * i, pa1A, pa2A);        // bperm-A on DS pipe
        // V-B reads queue BEHIND bperm-A (PV-A not delayed), ahead of bperm-B
        bf16x8 vfB[8];
        #pragma unroll
        for (int ec = 0; ec < 8; ++ec)
            vfB[ec] = *(const bf16x8*)(kbB + vfo[ec]);
        transform(S1B, S2B, 2 * i + 1, pa1B, pa2B);

        #pragma unroll
        for (int ec = 0; ec < 8; ++ec) {
            O1[ec] = __builtin_amdgcn_mfma_f32_16x16x32_bf16(pa1A, vfA[ec], O1[ec], 0, 0, 0);
            O2[ec] = __builtin_amdgcn_mfma_f32_16x16x32_bf16(pa2A, vfA[ec], O2[ec], 0, 0, 0);
        }
        #pragma unroll
        for (int ec = 0; ec < 8; ++ec) {
            O1[ec] = __builtin_amdgcn_mfma_f32_16x16x32_bf16(pa1B, vfB[ec], O1[ec], 0, 0, 0);
            O2[ec] = __builtin_amdgcn_mfma_f32_16x16x32_bf16(pa2B, vfB[ec], O2[ec], 0, 0, 0);
        }
    }

    // l sums: lane holds partial for row cl over its key-groups; reduce
    // across qd groups, then redistribute to output rows qd*4+r.
    l1s += __shfl_xor(l1s, 16); l1s += __shfl_xor(l1s, 32);
    l2s += __shfl_xor(l2s, 16); l2s += __shfl_xor(l2s, 32);
    float w1[4], w2[4];
    #pragma unroll
    for (int r = 0; r < 4; ++r) {
        float d1 = __shfl(l1s, qd * 4 + r);
        float d2 = __shfl(l2s, qd * 4 + r);
        w1[r] = 1.0f / d1;
        w2[r] = lamv / d2;
    }
    #pragma unroll
    for (int ec = 0; ec < 8; ++ec) {
        #pragma unroll
        for (int r = 0; r < 4; ++r) {
            size_t row = (size_t)(b * Tc + qrow + qd * 4 + r);
            attn[row * HVD + h * VDc + ec * 16 + cl] =
                f2bf(O1[ec][r] * w1[r] - O2[ec][r] * w2[r]);
        }
    }
}

// ---------------------------------------------------------------------------
// Fused row-stats + LayerNorm*0.2, in-place on bf16 attn. 128 thr/row.
// ---------------------------------------------------------------------------
__global__ __launch_bounds__(128) void ln_inplace(
    unsigned short* __restrict__ attn,
    const float* __restrict__ gnw, const float* __restrict__ gnb)
{
    int row = blockIdx.x, tid = threadIdx.x;
    unsigned short* p = attn + (size_t)row * HVD;
    float v[12];
    float s = 0.f, sq = 0.f;
    #pragma unroll
    for (int j = 0; j < 3; ++j) {
        int g = tid + j * 128;
        ushort4 u = *(const ushort4*)(p + g * 4);
        float x0 = bf2f(u.x), x1 = bf2f(u.y), x2 = bf2f(u.z), x3 = bf2f(u.w);
        v[j * 4 + 0] = x0; v[j * 4 + 1] = x1; v[j * 4 + 2] = x2; v[j * 4 + 3] = x3;
        s += x0 + x1 + x2 + x3;
        sq = fmaf(x0, x0, sq); sq = fmaf(x1, x1, sq);
        sq = fmaf(x2, x2, sq); sq = fmaf(x3, x3, sq);
    }
    #pragma unroll
    for (int off = 32; off; off >>= 1) { s += __shfl_xor(s, off); sq += __shfl_xor(sq, off); }
    __shared__ float ss[2], sqs[2];
    if ((tid & 63) == 0) { ss[tid >> 6] = s; sqs[tid >> 6] = sq; }
    __syncthreads();
    float S = ss[0] + ss[1], Q = sqs[0] + sqs[1];
    float mu = S * (1.0f / HVD);
    float rstd = rsqrtf(Q * (1.0f / HVD) - mu * mu + 1e-5f);
    #pragma unroll
    for (int j = 0; j < 3; ++j) {
        int g = tid + j * 128;
        float4 gw = *(const float4*)(gnw + g * 4);
        float4 gb = *(const float4*)(gnb + g * 4);
        ushort4 o;
        o.x = f2bf(((v[j * 4 + 0] - mu) * rstd * gw.x + gb.x) * 0.2f);
        o.y = f2bf(((v[j * 4 + 1] - mu) * rstd * gw.y + gb.y) * 0.2f);
        o.z = f2bf(((v[j * 4 + 2] - mu) * rstd * gw.z + gb.z) * 0.2f);
        o.w = f2bf(((v[j * 4 + 3] - mu) * rstd * gw.w + gb.w) * 0.2f);
        *(ushort4*)(p + g * 4) = o;
    }
}

// ---------------------------------------------------------------------------
// launch
// ---------------------------------------------------------------------------
extern "C" void kernel_launch(void* const* d_in, const int* in_sizes, int n_in,
                              void* d_out, int out_size, void* d_ws, size_t ws_size,
                              hipStream_t stream)
{
    const float* x   = (const float*)d_in[0];
    const float* Wq1 = (const float*)d_in[1];
    const float* Wk1 = (const float*)d_in[2];
    const float* Wq2 = (const float*)d_in[3];
    const float* Wk2 = (const float*)d_in[4];
    const float* Wv  = (const float*)d_in[5];
    const float* lq1 = (const float*)d_in[6];
    const float* lk1 = (const float*)d_in[7];
    const float* lq2 = (const float*)d_in[8];
    const float* lk2 = (const float*)d_in[9];
    const float* gnw = (const float*)d_in[10];
    const float* gnb = (const float*)d_in[11];
    const float* Wp  = (const float*)d_in[12];
    const float* bp  = (const float*)d_in[13];
    const int*   lidx = (const int*)d_in[14];
    float* out = (float*)d_out;

    // workspace layout (bytes):
    // WcatT bf16 [4608][768]:  7,077,888 @ 0
    // Xb    bf16 [4096][768]:  6,291,456 @ 7,077,888
    // Y     bf16 [4096][3072]: 25,165,824 @ 13,369,344
    // Vt    bf16 [48][128][1024]: 12,582,912 @ 38,535,168
    // attn  bf16 [4096][1536]: 12,582,912 @ 51,118,080
    // Wpb   bf16 [768][1536]:   2,359,296 @ 63,700,992
    // lam   f32 [12]                       @ 66,060,288
    char* w = (char*)d_ws;
    unsigned short* WcatT = (unsigned short*)(w);
    unsigned short* Xb    = (unsigned short*)(w + 7077888);
    unsigned short* Y     = (unsigned short*)(w + 13369344);
    unsigned short* VtW   = (unsigned short*)(w + 38535168);
    unsigned short* attn  = (unsigned short*)(w + 51118080);
    unsigned short* Wpb   = (unsigned short*)(w + 63700992);
    float* lam            = (float*)(w + 66060288);

    // fused casts + lambda + out zero-init + weight transpose (one launch)
    prep<<<dim3(8172), 256, 0, stream>>>(x, Wp, lq1, lk1, lq2, lk2, lidx,
                                         Wq1, Wk1, Wq2, Wk2, Wv,
                                         Xb, Wpb, lam, out, WcatT);
    // QKV: [4096,768] x [768,4608]; Q/K -> Y (LD 3072), V -> Vt transposed
    gemm_mfma<4, 768, YLD, false, true, 1><<<dim3(1152), 256, 0, stream>>>(
        Xb, WcatT, Y, nullptr, nullptr, VtW);
    // bh fastest (XCD pin); y -> g = 15-y, longest-first; 768 blocks x 4 waves
    diff_attn_mfma<<<dim3(Bc * Hc, 16), 256, 0, stream>>>(Y, VtW, lam, attn);
    ln_inplace<<<dim3(NROWS), 128, 0, stream>>>(attn, gnw, gnb);
    // OUT: [4096,1536] x [1536,768] -> out fp32 via split-K2 atomicAdd
    gemm_mfma<2, HVD, Cc, true, false, 2><<<dim3(768), 256, 0, stream>>>(
        attn, Wpb, nullptr, out, bp, nullptr);
}